// Round 3
// baseline (1261.672 us; speedup 1.0000x reference)
//
#include <hip/hip_runtime.h>

typedef unsigned short u16;
typedef unsigned int u32;
typedef __attribute__((ext_vector_type(8))) short short8;
typedef __attribute__((ext_vector_type(4))) float f32x4;

#define S_LEN 2048
#define E_DIM 4096
#define NHQ 32
#define NHKV 8
#define HD 128
#define CACHE_LEN 1024
#define T_LEN 3072

__device__ __forceinline__ u16 f2bf(float f) {
  union { float f; u32 u; } v; v.f = f;
  u32 u = v.u;
  return (u16)((u + 0x7FFFu + ((u >> 16) & 1u)) >> 16);
}

// ---------------------------------------------------------------------------
// x (fp32) -> bf16
__global__ __launch_bounds__(256) void cvt_x(const float* __restrict__ x,
                                             u16* __restrict__ xb) {
  int i = blockIdx.x * 256 + threadIdx.x;  // one float4 per thread
  float4 v = ((const float4*)x)[i];
  uint2 o;
  o.x = (u32)f2bf(v.x) | ((u32)f2bf(v.y) << 16);
  o.y = (u32)f2bf(v.z) | ((u32)f2bf(v.w) << 16);
  ((uint2*)xb)[i] = o;
}

// ---------------------------------------------------------------------------
// caches: fp32 copy into d_out K/V regions (t < 1024) + bf16 shadow
__global__ __launch_bounds__(256) void copy_caches(
    const float4* __restrict__ kc, const float4* __restrict__ vc,
    float4* __restrict__ Ko, float4* __restrict__ Vo,
    uint2* __restrict__ Kb, uint2* __restrict__ Vb) {
  int i = blockIdx.x * 256 + threadIdx.x;  // 262144 float4 (= 8*1024*128 elems)
  int h = i >> 15;                          // 32768 float4 per head
  size_t o = (size_t)i + ((size_t)h << 16); // dest head stride 3072*128
  float4 v = kc[i];
  Ko[o] = v;
  uint2 b;
  b.x = (u32)f2bf(v.x) | ((u32)f2bf(v.y) << 16);
  b.y = (u32)f2bf(v.z) | ((u32)f2bf(v.w) << 16);
  Kb[o] = b;
  v = vc[i];
  Vo[o] = v;
  b.x = (u32)f2bf(v.x) | ((u32)f2bf(v.y) << 16);
  b.y = (u32)f2bf(v.z) | ((u32)f2bf(v.w) << 16);
  Vb[o] = b;
}

// ---------------------------------------------------------------------------
// GEMM: C[M,N] = A[M,K](bf16) * B[K,N](fp32, converted on the fly)
// 128x128 tile, BK=32, 256 threads = 4 waves (2x2), 16x16x32 bf16 MFMA.
// MODE 0: write bf16 to outB[M][N]           (Q projection)
// MODE 1: write fp32+bf16 to K/V concat slot (KV projection, N=1024)
// MODE 2: write fp32 to outF[M][N]           (output projection)
template<int MODE>
__global__ __launch_bounds__(256) void gemm_bf16(
    const u16* __restrict__ A, const float* __restrict__ B,
    int M, int N, int K,
    float* __restrict__ outF, u16* __restrict__ outB) {
  __shared__ __align__(16) u16 Als[128][56];  // pitch 112B: 16B-aligned rows, ~2-way banks
  __shared__ __align__(16) u16 Bls[128][56];  // [n][k]
  const int tid = threadIdx.x;
  const int lane = tid & 63;
  const int wave = tid >> 6;
  const int wr = wave >> 1, wc = wave & 1;
  const int l15 = lane & 15, l4 = lane >> 4;
  const int nbn = N >> 7;
  const int bm0 = (blockIdx.x / nbn) << 7;
  const int bn0 = (blockIdx.x % nbn) << 7;

  f32x4 zero4; zero4[0] = 0.f; zero4[1] = 0.f; zero4[2] = 0.f; zero4[3] = 0.f;
  f32x4 acc[4][4];
#pragma unroll
  for (int i = 0; i < 4; ++i)
#pragma unroll
    for (int j = 0; j < 4; ++j) acc[i][j] = zero4;

  const int sbn = tid & 127;          // B staging: n
  const int sbk = (tid >> 7) << 4;    // B staging: k base (0 or 16)

  for (int k0 = 0; k0 < K; k0 += 32) {
    // stage A: 512 chunks of 8 bf16; 4 chunks per row
#pragma unroll
    for (int i = 0; i < 2; ++i) {
      int c = tid + (i << 8);
      int m = c >> 2, q = c & 3;
      const u16* src = A + (size_t)(bm0 + m) * K + k0 + (q << 3);
      *(uint4*)&Als[m][q << 3] = *(const uint4*)src;
    }
    // stage B transposed: thread reads a 16-deep column of w (coalesced across lanes)
    {
      const float* bsrc = B + (size_t)(k0 + sbk) * N + bn0 + sbn;
      float f[16];
#pragma unroll
      for (int j = 0; j < 16; ++j) f[j] = bsrc[(size_t)j * N];
      u32 us[8];
#pragma unroll
      for (int j = 0; j < 8; ++j)
        us[j] = (u32)f2bf(f[2 * j]) | ((u32)f2bf(f[2 * j + 1]) << 16);
      uint4 w0; w0.x = us[0]; w0.y = us[1]; w0.z = us[2]; w0.w = us[3];
      uint4 w1; w1.x = us[4]; w1.y = us[5]; w1.z = us[6]; w1.w = us[7];
      *(uint4*)&Bls[sbn][sbk] = w0;
      *(uint4*)&Bls[sbn][sbk + 8] = w1;
    }
    __syncthreads();
    short8 af[4], bfr[4];
#pragma unroll
    for (int mi = 0; mi < 4; ++mi)
      af[mi] = *(const short8*)&Als[(wr << 6) + (mi << 4) + l15][l4 << 3];
#pragma unroll
    for (int ni = 0; ni < 4; ++ni)
      bfr[ni] = *(const short8*)&Bls[(wc << 6) + (ni << 4) + l15][l4 << 3];
#pragma unroll
    for (int mi = 0; mi < 4; ++mi)
#pragma unroll
      for (int ni = 0; ni < 4; ++ni)
        acc[mi][ni] = __builtin_amdgcn_mfma_f32_16x16x32_bf16(af[mi], bfr[ni],
                                                              acc[mi][ni], 0, 0, 0);
    __syncthreads();
  }
  // epilogue; C/D layout: col = lane&15, row = (lane>>4)*4 + reg  [m89]
#pragma unroll
  for (int mi = 0; mi < 4; ++mi) {
#pragma unroll
    for (int ni = 0; ni < 4; ++ni) {
#pragma unroll
      for (int r = 0; r < 4; ++r) {
        int row = bm0 + (wr << 6) + (mi << 4) + (l4 << 2) + r;
        int col = bn0 + (wc << 6) + (ni << 4) + l15;
        float v = acc[mi][ni][r];
        if (MODE == 0) {
          outB[(size_t)row * N + col] = f2bf(v);
        } else if (MODE == 1) {
          int h = col >> 7, d = col & 127;
          size_t idx = ((size_t)h * T_LEN + (CACHE_LEN + row)) * HD + d;
          outF[idx] = v;
          outB[idx] = f2bf(v);
        } else {
          outF[(size_t)row * N + col] = v;
        }
      }
    }
  }
}

// ---------------------------------------------------------------------------
// Flash attention: block = (q-tile of 64) x (head). 4 waves, 16 q-rows each.
// KV tile = 32. QK^T and PV via 16x16x32 bf16 MFMA. Causal: t <= q + 1024.
__global__ __launch_bounds__(256) void attn_fwd(
    const u16* __restrict__ Qb, const u16* __restrict__ Kb,
    const u16* __restrict__ Vb, u16* __restrict__ resB) {
  __shared__ __align__(16) u16 Vls[128][56];     // V^T: [d][t]
  __shared__ __align__(16) u16 Pls[4][16][56];   // per-wave P: [q][t]
  const int tid = threadIdx.x;
  const int lane = tid & 63;
  const int wave = tid >> 6;
  const int l15 = lane & 15, l4 = lane >> 4;
  const int hq = blockIdx.y;
  const int kvh = hq & 7;              // reference maps head hq -> kv head hq % 8
  const int q0 = blockIdx.x << 6;
  const int qw = q0 + (wave << 4);

  // Q fragments live in registers for the whole kernel
  short8 aq[4];
  const u16* qrow = Qb + (size_t)(qw + l15) * E_DIM + hq * HD;
#pragma unroll
  for (int kd = 0; kd < 4; ++kd)
    aq[kd] = *(const short8*)(qrow + (kd << 5) + (l4 << 3));

  f32x4 accO[8];
  float mrow[4], lrow[4];
#pragma unroll
  for (int nd = 0; nd < 8; ++nd) {
    accO[nd][0] = 0.f; accO[nd][1] = 0.f; accO[nd][2] = 0.f; accO[nd][3] = 0.f;
  }
#pragma unroll
  for (int r = 0; r < 4; ++r) { mrow[r] = -1e30f; lrow[r] = 0.f; }

  const u16* Kh = Kb + (size_t)kvh * T_LEN * HD;
  const u16* Vh = Vb + (size_t)kvh * T_LEN * HD;
  const int nt = (q0 + 1088) >> 5;     // all rows' allowed keys covered
  const int stl = tid & 31, sdc = (tid >> 5) << 4;

  for (int it = 0; it < nt; ++it) {
    const int t0 = it << 5;
    __syncthreads();  // previous PV done before Vls overwrite
    {   // stage V^T tile: rows coalesced from global, scatter to [d][t]
      const u16* vsrc = Vh + (size_t)(t0 + stl) * HD + sdc;
      short8 v0 = *(const short8*)vsrc;
      short8 v1 = *(const short8*)(vsrc + 8);
#pragma unroll
      for (int j = 0; j < 8; ++j) Vls[sdc + j][stl] = (u16)v0[j];
#pragma unroll
      for (int j = 0; j < 8; ++j) Vls[sdc + 8 + j][stl] = (u16)v1[j];
    }
    __syncthreads();

    // QK^T: contract d=128 in 4 chunks; K rows are the B operand (k = d)
    f32x4 sc0, sc1;
    sc0[0]=0.f; sc0[1]=0.f; sc0[2]=0.f; sc0[3]=0.f;
    sc1[0]=0.f; sc1[1]=0.f; sc1[2]=0.f; sc1[3]=0.f;
#pragma unroll
    for (int kd = 0; kd < 4; ++kd) {
      short8 bk0 = *(const short8*)(Kh + (size_t)(t0 + l15) * HD + (kd << 5) + (l4 << 3));
      short8 bk1 = *(const short8*)(Kh + (size_t)(t0 + 16 + l15) * HD + (kd << 5) + (l4 << 3));
      sc0 = __builtin_amdgcn_mfma_f32_16x16x32_bf16(aq[kd], bk0, sc0, 0, 0, 0);
      sc1 = __builtin_amdgcn_mfma_f32_16x16x32_bf16(aq[kd], bk1, sc1, 0, 0, 0);
    }

    const float scale = 0.08838834764831845f;  // 1/sqrt(128)
    float s0[4], s1[4];
    const bool need_mask = (t0 + 31) > (q0 + CACHE_LEN);
#pragma unroll
    for (int r = 0; r < 4; ++r) {
      float a = sc0[r] * scale;
      float b = sc1[r] * scale;
      if (need_mask) {
        int qq = qw + (l4 << 2) + r + CACHE_LEN;
        if (t0 + l15 > qq) a = -1e30f;
        if (t0 + 16 + l15 > qq) b = -1e30f;
      }
      s0[r] = a; s1[r] = b;
    }
    // online softmax, per q-row (row stats live in all 16 lanes of the group)
#pragma unroll
    for (int r = 0; r < 4; ++r) {
      float m = fmaxf(s0[r], s1[r]);
      m = fmaxf(m, __shfl_xor(m, 1));
      m = fmaxf(m, __shfl_xor(m, 2));
      m = fmaxf(m, __shfl_xor(m, 4));
      m = fmaxf(m, __shfl_xor(m, 8));
      float mn = fmaxf(mrow[r], m);
      float corr = __expf(mrow[r] - mn);
      mrow[r] = mn;
      float p0 = __expf(s0[r] - mn);
      float p1 = __expf(s1[r] - mn);
      s0[r] = p0; s1[r] = p1;
      float rs = p0 + p1;
      rs += __shfl_xor(rs, 1);
      rs += __shfl_xor(rs, 2);
      rs += __shfl_xor(rs, 4);
      rs += __shfl_xor(rs, 8);
      lrow[r] = lrow[r] * corr + rs;
#pragma unroll
      for (int nd = 0; nd < 8; ++nd) accO[nd][r] *= corr;
    }
    // P (D-layout) -> LDS -> A-fragment layout (wave-private, no barrier)
#pragma unroll
    for (int r = 0; r < 4; ++r) {
      Pls[wave][(l4 << 2) + r][l15] = f2bf(s0[r]);
      Pls[wave][(l4 << 2) + r][16 + l15] = f2bf(s1[r]);
    }
    short8 pa = *(const short8*)&Pls[wave][l15][l4 << 3];
#pragma unroll
    for (int nd = 0; nd < 8; ++nd) {
      short8 bv = *(const short8*)&Vls[(nd << 4) + l15][l4 << 3];
      accO[nd] = __builtin_amdgcn_mfma_f32_16x16x32_bf16(pa, bv, accO[nd], 0, 0, 0);
    }
  }
  // finalize: divide by softmax denom, write bf16 res[s][hq*128+d]
#pragma unroll
  for (int nd = 0; nd < 8; ++nd) {
#pragma unroll
    for (int r = 0; r < 4; ++r) {
      float v = accO[nd][r] / lrow[r];
      int q = qw + (l4 << 2) + r;
      int d = (nd << 4) + l15;
      resB[(size_t)q * E_DIM + hq * HD + d] = f2bf(v);
    }
  }
}

// ---------------------------------------------------------------------------
extern "C" void kernel_launch(void* const* d_in, const int* in_sizes, int n_in,
                              void* d_out, int out_size, void* d_ws, size_t ws_size,
                              hipStream_t stream) {
  const float* x = (const float*)d_in[0];
  const float* w_q = (const float*)d_in[1];
  const float* w_k = (const float*)d_in[2];
  const float* w_v = (const float*)d_in[3];
  const float* w_o = (const float*)d_in[4];
  const float* k_cache = (const float*)d_in[5];
  const float* v_cache = (const float*)d_in[6];
  // d_in[7] = attention_mask: exactly causal-with-offset; applied analytically.

  float* out = (float*)d_out;                          // [2048][4096]
  float* Kout = out + (size_t)S_LEN * E_DIM;           // [8][3072][128]
  float* Vout = Kout + (size_t)NHKV * T_LEN * HD;      // [8][3072][128]

  // workspace layout (60 MiB):
  char* ws = (char*)d_ws;
  u16* xb = (u16*)(ws);                                // 16 MiB  x bf16
  u16* Qb = (u16*)(ws + (size_t)16 * 1024 * 1024);     // 16 MiB  Q bf16 [s][e]
  u16* resB = (u16*)(ws + (size_t)32 * 1024 * 1024);   // 16 MiB  attn out bf16
  u16* Kb = (u16*)(ws + (size_t)48 * 1024 * 1024);     // 6 MiB   K bf16 [8][3072][128]
  u16* Vb = (u16*)(ws + (size_t)54 * 1024 * 1024);     // 6 MiB   V bf16

  cvt_x<<<dim3(8192), dim3(256), 0, stream>>>(x, xb);
  copy_caches<<<dim3(1024), dim3(256), 0, stream>>>(
      (const float4*)k_cache, (const float4*)v_cache,
      (float4*)Kout, (float4*)Vout, (uint2*)Kb, (uint2*)Vb);
  gemm_bf16<1><<<dim3(16 * 8), dim3(256), 0, stream>>>(xb, w_k, S_LEN, NHKV * HD, E_DIM, Kout, Kb);
  gemm_bf16<1><<<dim3(16 * 8), dim3(256), 0, stream>>>(xb, w_v, S_LEN, NHKV * HD, E_DIM, Vout, Vb);
  gemm_bf16<0><<<dim3(16 * 32), dim3(256), 0, stream>>>(xb, w_q, S_LEN, E_DIM, E_DIM, nullptr, Qb);
  attn_fwd<<<dim3(32, 32), dim3(256), 0, stream>>>(Qb, Kb, Vb, resB);
  gemm_bf16<2><<<dim3(16 * 32), dim3(256), 0, stream>>>(resB, w_o, S_LEN, E_DIM, E_DIM, out, nullptr);
}

// Round 4
// 989.425 us; speedup vs baseline: 1.2752x; 1.2752x over previous
//
#include <hip/hip_runtime.h>

typedef unsigned short u16;
typedef unsigned int u32;
typedef __attribute__((ext_vector_type(8))) short short8;
typedef __attribute__((ext_vector_type(4))) float f32x4;

#define S_LEN 2048
#define E_DIM 4096
#define NHQ 32
#define NHKV 8
#define HD 128
#define CACHE_LEN 1024
#define T_LEN 3072
#define KV_ELEMS ((size_t)NHKV * T_LEN * HD)   // 3145728

__device__ __forceinline__ u16 f2bf(float f) {
  union { float f; u32 u; } v; v.f = f;
  u32 u = v.u;
  return (u16)((u + 0x7FFFu + ((u >> 16) & 1u)) >> 16);
}

// global -> LDS direct copy, 16 bytes per lane (linear LDS dest)
__device__ __forceinline__ void gl_lds16(const void* g, void* l) {
  __builtin_amdgcn_global_load_lds(
      (const __attribute__((address_space(1))) unsigned int*)g,
      (__attribute__((address_space(3))) unsigned int*)l, 16, 0, 0);
}

// ---------------------------------------------------------------------------
// x (fp32) -> bf16
__global__ __launch_bounds__(256) void cvt_x(const float* __restrict__ x,
                                             u16* __restrict__ xb) {
  int i = blockIdx.x * 256 + threadIdx.x;  // one float4 per thread
  float4 v = ((const float4*)x)[i];
  uint2 o;
  o.x = (u32)f2bf(v.x) | ((u32)f2bf(v.y) << 16);
  o.y = (u32)f2bf(v.z) | ((u32)f2bf(v.w) << 16);
  ((uint2*)xb)[i] = o;
}

// ---------------------------------------------------------------------------
// caches: fp32 copy into d_out K/V regions (t < 1024) + bf16 shadow
__global__ __launch_bounds__(256) void copy_caches(
    const float4* __restrict__ kc, const float4* __restrict__ vc,
    float4* __restrict__ Ko, float4* __restrict__ Vo,
    uint2* __restrict__ Kb, uint2* __restrict__ Vb) {
  int i = blockIdx.x * 256 + threadIdx.x;  // 262144 float4 (= 8*1024*128 elems)
  int h = i >> 15;                          // 32768 float4 per head
  size_t o = (size_t)i + ((size_t)h << 16); // dest head stride 3072*128
  float4 v = kc[i];
  Ko[o] = v;
  uint2 b;
  b.x = (u32)f2bf(v.x) | ((u32)f2bf(v.y) << 16);
  b.y = (u32)f2bf(v.z) | ((u32)f2bf(v.w) << 16);
  Kb[o] = b;
  v = vc[i];
  Vo[o] = v;
  b.x = (u32)f2bf(v.x) | ((u32)f2bf(v.y) << 16);
  b.y = (u32)f2bf(v.z) | ((u32)f2bf(v.w) << 16);
  Vb[o] = b;
}

// ---------------------------------------------------------------------------
// weight transpose + convert: w fp32 [K][N] -> wt bf16 [N][K]. 64x64 tiles.
__global__ __launch_bounds__(256) void cvt_wt(const float* __restrict__ w,
                                              u16* __restrict__ wt,
                                              int K, int N) {
  __shared__ u16 t[64][68];   // pitch 68 u16: breaks write bank aliasing
  const int tid = threadIdx.x;
  const int ntk = K >> 6;
  const int k0 = (blockIdx.x % ntk) << 6;
  const int n0 = (blockIdx.x / ntk) << 6;
  const int kl = tid >> 4;          // 0..15
  const int nl4 = (tid & 15) << 2;  // 0..60
#pragma unroll
  for (int i = 0; i < 4; ++i) {
    int kk = kl + (i << 4);
    float4 v = *(const float4*)&w[(size_t)(k0 + kk) * N + n0 + nl4];
    t[nl4 + 0][kk] = f2bf(v.x);
    t[nl4 + 1][kk] = f2bf(v.y);
    t[nl4 + 2][kk] = f2bf(v.z);
    t[nl4 + 3][kk] = f2bf(v.w);
  }
  __syncthreads();
  const int onl = tid >> 3;        // 0..31
  const int okc = (tid & 7) << 3;  // 0..56
#pragma unroll
  for (int p = 0; p < 2; ++p) {
    int nl = onl + (p << 5);
    u32 a0 = (u32)t[nl][okc + 0] | ((u32)t[nl][okc + 1] << 16);
    u32 a1 = (u32)t[nl][okc + 2] | ((u32)t[nl][okc + 3] << 16);
    u32 a2 = (u32)t[nl][okc + 4] | ((u32)t[nl][okc + 5] << 16);
    u32 a3 = (u32)t[nl][okc + 6] | ((u32)t[nl][okc + 7] << 16);
    uint4 o4; o4.x = a0; o4.y = a1; o4.z = a2; o4.w = a3;
    *(uint4*)&wt[(size_t)(n0 + nl) * K + k0 + okc] = o4;
  }
}

// ---------------------------------------------------------------------------
// m97-structure GEMM: C[M,N] = A[M,K](bf16) * Bt[N,K](bf16)^T
// 128x128 tile, BK=32, 4 waves (2x2), linear LDS + global_load_lds width 16.
// MODE 0: bf16 -> outB[M][N]              (Q projection)
// MODE 1: fp32+bf16 -> K/V concat slots   (fused KV projection, N=2048)
// MODE 2: fp32 -> outF[M][N]              (output projection)
template<int MODE>
__global__ __launch_bounds__(256) void gemm2(
    const u16* __restrict__ A, const u16* __restrict__ Bt,
    int M, int N, int K,
    float* __restrict__ outF, u16* __restrict__ outB) {
  __shared__ __align__(16) u16 Als[128 * 32];
  __shared__ __align__(16) u16 Bls[128 * 32];
  const int tid = threadIdx.x;
  const int lane = tid & 63;
  const int wave = tid >> 6;
  const int wr = wave >> 1, wc = wave & 1;
  const int l15 = lane & 15, l4 = lane >> 4;
  const int nbn = N >> 7;
  const int bm0 = (blockIdx.x / nbn) << 7;
  const int bn0 = (blockIdx.x % nbn) << 7;

  f32x4 acc[4][4];
#pragma unroll
  for (int i = 0; i < 4; ++i)
#pragma unroll
    for (int j = 0; j < 4; ++j) {
      acc[i][j][0] = 0.f; acc[i][j][1] = 0.f;
      acc[i][j][2] = 0.f; acc[i][j][3] = 0.f;
    }

  const u16* Abase = A + (size_t)bm0 * K;
  const u16* Bbase = Bt + (size_t)bn0 * K;
  // staging: chunk c in [0,512): row=c>>2, k-col=(c&3)*8, LDS elem off = c*8
  const int c0 = tid, c1 = tid + 256;
  const int r0 = c0 >> 2, q0c = (c0 & 3) << 3;
  const int r1 = c1 >> 2, q1c = (c1 & 3) << 3;

  for (int k0 = 0; k0 < K; k0 += 32) {
    __syncthreads();  // previous iteration's ds_reads complete before overwrite
    gl_lds16(Abase + (size_t)r0 * K + k0 + q0c, &Als[c0 << 3]);
    gl_lds16(Bbase + (size_t)r0 * K + k0 + q0c, &Bls[c0 << 3]);
    gl_lds16(Abase + (size_t)r1 * K + k0 + q1c, &Als[c1 << 3]);
    gl_lds16(Bbase + (size_t)r1 * K + k0 + q1c, &Bls[c1 << 3]);
    __syncthreads();  // drains vmcnt(0): staged tile visible to all waves

    short8 af[4], bfr[4];
#pragma unroll
    for (int mi = 0; mi < 4; ++mi)
      af[mi] = *(const short8*)&Als[((wr << 6) + (mi << 4) + l15) * 32 + (l4 << 3)];
#pragma unroll
    for (int ni = 0; ni < 4; ++ni)
      bfr[ni] = *(const short8*)&Bls[((wc << 6) + (ni << 4) + l15) * 32 + (l4 << 3)];
#pragma unroll
    for (int mi = 0; mi < 4; ++mi)
#pragma unroll
      for (int ni = 0; ni < 4; ++ni)
        acc[mi][ni] = __builtin_amdgcn_mfma_f32_16x16x32_bf16(af[mi], bfr[ni],
                                                              acc[mi][ni], 0, 0, 0);
  }
  // epilogue; C/D layout: col = lane&15, row = (lane>>4)*4 + reg  [m89]
#pragma unroll
  for (int mi = 0; mi < 4; ++mi) {
#pragma unroll
    for (int ni = 0; ni < 4; ++ni) {
#pragma unroll
      for (int r = 0; r < 4; ++r) {
        int row = bm0 + (wr << 6) + (mi << 4) + (l4 << 2) + r;
        int col = bn0 + (wc << 6) + (ni << 4) + l15;
        float v = acc[mi][ni][r];
        if (MODE == 0) {
          outB[(size_t)row * N + col] = f2bf(v);
        } else if (MODE == 1) {
          int hv = col >> 7;   // 0..7 = K heads, 8..15 = V heads
          int d = col & 127;
          size_t idx = ((size_t)(hv & 7) * T_LEN + (CACHE_LEN + row)) * HD + d
                     + ((hv >= 8) ? KV_ELEMS : (size_t)0);
          outF[idx] = v;
          outB[idx] = f2bf(v);
        } else {
          outF[(size_t)row * N + col] = v;
        }
      }
    }
  }
}

// ---------------------------------------------------------------------------
// Flash attention: block = (q-tile of 64) x (head). 4 waves, 16 q-rows each.
// KV tile = 32. QK^T and PV via 16x16x32 bf16 MFMA. Causal: t <= q + 1024.
__global__ __launch_bounds__(256) void attn_fwd(
    const u16* __restrict__ Qb, const u16* __restrict__ Kb,
    const u16* __restrict__ Vb, u16* __restrict__ resB) {
  __shared__ __align__(16) u16 Vls[128][56];     // V^T: [d][t]
  __shared__ __align__(16) u16 Pls[4][16][56];   // per-wave P: [q][t]
  const int tid = threadIdx.x;
  const int lane = tid & 63;
  const int wave = tid >> 6;
  const int l15 = lane & 15, l4 = lane >> 4;
  const int hq = blockIdx.y;
  const int kvh = hq & 7;              // reference maps head hq -> kv head hq % 8
  const int q0 = blockIdx.x << 6;
  const int qw = q0 + (wave << 4);

  short8 aq[4];
  const u16* qrow = Qb + (size_t)(qw + l15) * E_DIM + hq * HD;
#pragma unroll
  for (int kd = 0; kd < 4; ++kd)
    aq[kd] = *(const short8*)(qrow + (kd << 5) + (l4 << 3));

  f32x4 accO[8];
  float mrow[4], lrow[4];
#pragma unroll
  for (int nd = 0; nd < 8; ++nd) {
    accO[nd][0] = 0.f; accO[nd][1] = 0.f; accO[nd][2] = 0.f; accO[nd][3] = 0.f;
  }
#pragma unroll
  for (int r = 0; r < 4; ++r) { mrow[r] = -1e30f; lrow[r] = 0.f; }

  const u16* Kh = Kb + (size_t)kvh * T_LEN * HD;
  const u16* Vh = Vb + (size_t)kvh * T_LEN * HD;
  const int nt = (q0 + 1088) >> 5;
  const int stl = tid & 31, sdc = (tid >> 5) << 4;

  for (int it = 0; it < nt; ++it) {
    const int t0 = it << 5;
    __syncthreads();
    {   // stage V^T tile
      const u16* vsrc = Vh + (size_t)(t0 + stl) * HD + sdc;
      short8 v0 = *(const short8*)vsrc;
      short8 v1 = *(const short8*)(vsrc + 8);
#pragma unroll
      for (int j = 0; j < 8; ++j) Vls[sdc + j][stl] = (u16)v0[j];
#pragma unroll
      for (int j = 0; j < 8; ++j) Vls[sdc + 8 + j][stl] = (u16)v1[j];
    }
    __syncthreads();

    f32x4 sc0, sc1;
    sc0[0]=0.f; sc0[1]=0.f; sc0[2]=0.f; sc0[3]=0.f;
    sc1[0]=0.f; sc1[1]=0.f; sc1[2]=0.f; sc1[3]=0.f;
#pragma unroll
    for (int kd = 0; kd < 4; ++kd) {
      short8 bk0 = *(const short8*)(Kh + (size_t)(t0 + l15) * HD + (kd << 5) + (l4 << 3));
      short8 bk1 = *(const short8*)(Kh + (size_t)(t0 + 16 + l15) * HD + (kd << 5) + (l4 << 3));
      sc0 = __builtin_amdgcn_mfma_f32_16x16x32_bf16(aq[kd], bk0, sc0, 0, 0, 0);
      sc1 = __builtin_amdgcn_mfma_f32_16x16x32_bf16(aq[kd], bk1, sc1, 0, 0, 0);
    }

    const float scale = 0.08838834764831845f;  // 1/sqrt(128)
    float s0[4], s1[4];
    const bool need_mask = (t0 + 31) > (q0 + CACHE_LEN);
#pragma unroll
    for (int r = 0; r < 4; ++r) {
      float a = sc0[r] * scale;
      float b = sc1[r] * scale;
      if (need_mask) {
        int qq = qw + (l4 << 2) + r + CACHE_LEN;
        if (t0 + l15 > qq) a = -1e30f;
        if (t0 + 16 + l15 > qq) b = -1e30f;
      }
      s0[r] = a; s1[r] = b;
    }
#pragma unroll
    for (int r = 0; r < 4; ++r) {
      float m = fmaxf(s0[r], s1[r]);
      m = fmaxf(m, __shfl_xor(m, 1));
      m = fmaxf(m, __shfl_xor(m, 2));
      m = fmaxf(m, __shfl_xor(m, 4));
      m = fmaxf(m, __shfl_xor(m, 8));
      float mn = fmaxf(mrow[r], m);
      float corr = __expf(mrow[r] - mn);
      mrow[r] = mn;
      float p0 = __expf(s0[r] - mn);
      float p1 = __expf(s1[r] - mn);
      s0[r] = p0; s1[r] = p1;
      float rs = p0 + p1;
      rs += __shfl_xor(rs, 1);
      rs += __shfl_xor(rs, 2);
      rs += __shfl_xor(rs, 4);
      rs += __shfl_xor(rs, 8);
      lrow[r] = lrow[r] * corr + rs;
#pragma unroll
      for (int nd = 0; nd < 8; ++nd) accO[nd][r] *= corr;
    }
#pragma unroll
    for (int r = 0; r < 4; ++r) {
      Pls[wave][(l4 << 2) + r][l15] = f2bf(s0[r]);
      Pls[wave][(l4 << 2) + r][16 + l15] = f2bf(s1[r]);
    }
    short8 pa = *(const short8*)&Pls[wave][l15][l4 << 3];
#pragma unroll
    for (int nd = 0; nd < 8; ++nd) {
      short8 bv = *(const short8*)&Vls[(nd << 4) + l15][l4 << 3];
      accO[nd] = __builtin_amdgcn_mfma_f32_16x16x32_bf16(pa, bv, accO[nd], 0, 0, 0);
    }
  }
#pragma unroll
  for (int nd = 0; nd < 8; ++nd) {
#pragma unroll
    for (int r = 0; r < 4; ++r) {
      float v = accO[nd][r] / lrow[r];
      int q = qw + (l4 << 2) + r;
      int d = (nd << 4) + l15;
      resB[(size_t)q * E_DIM + hq * HD + d] = f2bf(v);
    }
  }
}

// ---------------------------------------------------------------------------
extern "C" void kernel_launch(void* const* d_in, const int* in_sizes, int n_in,
                              void* d_out, int out_size, void* d_ws, size_t ws_size,
                              hipStream_t stream) {
  const float* x = (const float*)d_in[0];
  const float* w_q = (const float*)d_in[1];
  const float* w_k = (const float*)d_in[2];
  const float* w_v = (const float*)d_in[3];
  const float* w_o = (const float*)d_in[4];
  const float* k_cache = (const float*)d_in[5];
  const float* v_cache = (const float*)d_in[6];
  // d_in[7] = attention_mask: causal-with-offset; applied analytically.

  float* out = (float*)d_out;                          // [2048][4096]
  float* Kout = out + (size_t)S_LEN * E_DIM;           // [8][3072][128]
  // Vout = Kout + KV_ELEMS (MODE 1 epilogue adds the offset)

  // workspace layout (96 MiB), with region reuse:
  //   [ 0,16)  xb   (x bf16)          -> reused as resB after Q-GEMM
  //   [16,32)  Qb   (Q bf16)
  //   [32,38)  Kb   (K bf16 shadow)   [38,44) Vb   (V bf16 shadow)
  //   [48,64)  wkvt (w_k^T | w_v^T bf16, [2048][4096])
  //   [64,96)  wbig (w_q^T bf16, then reused for w_o^T)
  char* ws = (char*)d_ws;
  const size_t MB = 1024 * 1024;
  u16* xb   = (u16*)(ws);
  u16* resB = (u16*)(ws);
  u16* Qb   = (u16*)(ws + 16 * MB);
  u16* Kb   = (u16*)(ws + 32 * MB);
  u16* Vb   = (u16*)(ws + 38 * MB);
  u16* wkvt = (u16*)(ws + 48 * MB);
  u16* wbig = (u16*)(ws + 64 * MB);

  cvt_x<<<dim3(8192), dim3(256), 0, stream>>>(x, xb);
  copy_caches<<<dim3(1024), dim3(256), 0, stream>>>(
      (const float4*)k_cache, (const float4*)v_cache,
      (float4*)Kout, (float4*)(Kout + KV_ELEMS), (uint2*)Kb, (uint2*)Vb);
  cvt_wt<<<dim3(1024), dim3(256), 0, stream>>>(w_k, wkvt, E_DIM, NHKV * HD);
  cvt_wt<<<dim3(1024), dim3(256), 0, stream>>>(w_v, wkvt + (size_t)1024 * E_DIM, E_DIM, NHKV * HD);
  cvt_wt<<<dim3(4096), dim3(256), 0, stream>>>(w_q, wbig, E_DIM, E_DIM);
  gemm2<1><<<dim3(16 * 16), dim3(256), 0, stream>>>(xb, wkvt, S_LEN, 2048, E_DIM, Kout, Kb);
  gemm2<0><<<dim3(16 * 32), dim3(256), 0, stream>>>(xb, wbig, S_LEN, E_DIM, E_DIM, nullptr, Qb);
  cvt_wt<<<dim3(4096), dim3(256), 0, stream>>>(w_o, wbig, E_DIM, E_DIM);
  attn_fwd<<<dim3(32, 32), dim3(256), 0, stream>>>(Qb, Kb, Vb, resB);
  gemm2<2><<<dim3(16 * 32), dim3(256), 0, stream>>>(resB, wbig, S_LEN, E_DIM, E_DIM, out, nullptr);
}

// Round 7
// 793.189 us; speedup vs baseline: 1.5906x; 1.2474x over previous
//
#include <hip/hip_runtime.h>

typedef unsigned short u16;
typedef unsigned int u32;
typedef __attribute__((ext_vector_type(8))) short short8;
typedef __attribute__((ext_vector_type(4))) float f32x4;

#define S_LEN 2048
#define E_DIM 4096
#define NHQ 32
#define NHKV 8
#define HD 128
#define CACHE_LEN 1024
#define T_LEN 3072
#define KV_ELEMS ((size_t)NHKV * T_LEN * HD)   // 3145728

__device__ __forceinline__ u16 f2bf(float f) {
  union { float f; u32 u; } v; v.f = f;
  u32 u = v.u;
  return (u16)((u + 0x7FFFu + ((u >> 16) & 1u)) >> 16);
}

// global -> LDS direct copy, 16 bytes per lane (wave-uniform LDS base, HW adds lane*16)
__device__ __forceinline__ void gl_lds16(const void* g, void* l) {
  __builtin_amdgcn_global_load_lds(
      (const __attribute__((address_space(1))) unsigned int*)g,
      (__attribute__((address_space(3))) unsigned int*)l, 16, 0, 0);
}

// ---------------------------------------------------------------------------
// x (fp32) -> bf16
__global__ __launch_bounds__(256) void cvt_x(const float* __restrict__ x,
                                             u16* __restrict__ xb) {
  int i = blockIdx.x * 256 + threadIdx.x;
  float4 v = ((const float4*)x)[i];
  uint2 o;
  o.x = (u32)f2bf(v.x) | ((u32)f2bf(v.y) << 16);
  o.y = (u32)f2bf(v.z) | ((u32)f2bf(v.w) << 16);
  ((uint2*)xb)[i] = o;
}

// ---------------------------------------------------------------------------
// caches: fp32 copy into d_out K/V regions (t < 1024) + K bf16 shadow (row-major)
__global__ __launch_bounds__(256) void copy_caches(
    const float4* __restrict__ kc, const float4* __restrict__ vc,
    float4* __restrict__ Ko, float4* __restrict__ Vo,
    uint2* __restrict__ Kb) {
  int i = blockIdx.x * 256 + threadIdx.x;  // 262144 float4
  int h = i >> 15;
  size_t o = (size_t)i + ((size_t)h << 16);
  float4 v = kc[i];
  Ko[o] = v;
  uint2 b;
  b.x = (u32)f2bf(v.x) | ((u32)f2bf(v.y) << 16);
  b.y = (u32)f2bf(v.z) | ((u32)f2bf(v.w) << 16);
  Kb[o] = b;
  Vo[o] = vc[i];
}

// ---------------------------------------------------------------------------
// v_cache fp32 [h][1024][128] -> V^T bf16 [h][128][3072] (cols 0..1023), LDS-tiled
__global__ __launch_bounds__(256) void cvt_vcT(const float* __restrict__ vc,
                                               u16* __restrict__ vbT) {
  __shared__ u16 t[64][68];
  const int tid = threadIdx.x;
  const int h = blockIdx.z;
  const int t0 = blockIdx.x << 6;   // 16 t-tiles
  const int d0 = blockIdx.y << 6;   // 2 d-tiles
  const float* in = vc + ((size_t)h * CACHE_LEN + t0) * HD + d0;
  const int rl = tid >> 4;
  const int c4 = (tid & 15) << 2;
#pragma unroll
  for (int i = 0; i < 4; ++i) {
    int rr = rl + (i << 4);
    float4 v = *(const float4*)&in[(size_t)rr * HD + c4];
    t[c4 + 0][rr] = f2bf(v.x);
    t[c4 + 1][rr] = f2bf(v.y);
    t[c4 + 2][rr] = f2bf(v.z);
    t[c4 + 3][rr] = f2bf(v.w);
  }
  __syncthreads();
  u16* outp = vbT + ((size_t)h * HD + d0) * T_LEN + t0;
#pragma unroll
  for (int p = 0; p < 2; ++p) {
    int idx = tid + (p << 8);
    int dr = idx >> 3;
    int ch = (idx & 7) << 3;
    u32 a0 = (u32)t[dr][ch + 0] | ((u32)t[dr][ch + 1] << 16);
    u32 a1 = (u32)t[dr][ch + 2] | ((u32)t[dr][ch + 3] << 16);
    u32 a2 = (u32)t[dr][ch + 4] | ((u32)t[dr][ch + 5] << 16);
    u32 a3 = (u32)t[dr][ch + 6] | ((u32)t[dr][ch + 7] << 16);
    uint4 o4; o4.x = a0; o4.y = a1; o4.z = a2; o4.w = a3;
    *(uint4*)&outp[(size_t)dr * T_LEN + ch] = o4;
  }
}

// ---------------------------------------------------------------------------
// weight transpose + convert: w fp32 [K][N] -> wt bf16 [N][K]. 64x64 tiles.
__global__ __launch_bounds__(256) void cvt_wt(const float* __restrict__ w,
                                              u16* __restrict__ wt,
                                              int K, int N) {
  __shared__ u16 t[64][68];
  const int tid = threadIdx.x;
  const int ntk = K >> 6;
  const int k0 = (blockIdx.x % ntk) << 6;
  const int n0 = (blockIdx.x / ntk) << 6;
  const int kl = tid >> 4;
  const int nl4 = (tid & 15) << 2;
#pragma unroll
  for (int i = 0; i < 4; ++i) {
    int kk = kl + (i << 4);
    float4 v = *(const float4*)&w[(size_t)(k0 + kk) * N + n0 + nl4];
    t[nl4 + 0][kk] = f2bf(v.x);
    t[nl4 + 1][kk] = f2bf(v.y);
    t[nl4 + 2][kk] = f2bf(v.z);
    t[nl4 + 3][kk] = f2bf(v.w);
  }
  __syncthreads();
  const int onl = tid >> 3;
  const int okc = (tid & 7) << 3;
#pragma unroll
  for (int p = 0; p < 2; ++p) {
    int nl = onl + (p << 5);
    u32 a0 = (u32)t[nl][okc + 0] | ((u32)t[nl][okc + 1] << 16);
    u32 a1 = (u32)t[nl][okc + 2] | ((u32)t[nl][okc + 3] << 16);
    u32 a2 = (u32)t[nl][okc + 4] | ((u32)t[nl][okc + 5] << 16);
    u32 a3 = (u32)t[nl][okc + 6] | ((u32)t[nl][okc + 7] << 16);
    uint4 o4; o4.x = a0; o4.y = a1; o4.z = a2; o4.w = a3;
    *(uint4*)&wt[(size_t)(n0 + nl) * K + k0 + okc] = o4;
  }
}

// ---------------------------------------------------------------------------
// m97-structure GEMM: C[M,N] = A[M,K](bf16) * Bt[N,K](bf16)^T
// MODE 0: bf16 -> outB[M][N]                   (Q projection)
// MODE 1: fp32 + shadows -> K/V concat slots   (fused KV projection, N=2048;
//          K shadow row-major in outB, V shadow transposed in outB2)
// MODE 2: fp32 -> outF[M][N]                   (output projection)
template<int MODE>
__global__ __launch_bounds__(256) void gemm2(
    const u16* __restrict__ A, const u16* __restrict__ Bt,
    int M, int N, int K,
    float* __restrict__ outF, u16* __restrict__ outB, u16* __restrict__ outB2) {
  __shared__ __align__(16) u16 Als[128 * 32];
  __shared__ __align__(16) u16 Bls[128 * 32];
  const int tid = threadIdx.x;
  const int lane = tid & 63;
  const int wave = tid >> 6;
  const int wr = wave >> 1, wc = wave & 1;
  const int l15 = lane & 15, l4 = lane >> 4;
  const int nbn = N >> 7;
  const int bm0 = (blockIdx.x / nbn) << 7;
  const int bn0 = (blockIdx.x % nbn) << 7;

  f32x4 acc[4][4];
#pragma unroll
  for (int i = 0; i < 4; ++i)
#pragma unroll
    for (int j = 0; j < 4; ++j) {
      acc[i][j][0] = 0.f; acc[i][j][1] = 0.f;
      acc[i][j][2] = 0.f; acc[i][j][3] = 0.f;
    }

  const u16* Abase = A + (size_t)bm0 * K;
  const u16* Bbase = Bt + (size_t)bn0 * K;
  const int c0 = tid, c1 = tid + 256;
  const int r0 = c0 >> 2, q0c = (c0 & 3) << 3;
  const int r1 = c1 >> 2, q1c = (c1 & 3) << 3;

  for (int k0 = 0; k0 < K; k0 += 32) {
    __syncthreads();
    gl_lds16(Abase + (size_t)r0 * K + k0 + q0c, &Als[c0 << 3]);
    gl_lds16(Bbase + (size_t)r0 * K + k0 + q0c, &Bls[c0 << 3]);
    gl_lds16(Abase + (size_t)r1 * K + k0 + q1c, &Als[c1 << 3]);
    gl_lds16(Bbase + (size_t)r1 * K + k0 + q1c, &Bls[c1 << 3]);
    __syncthreads();

    short8 af[4], bfr[4];
#pragma unroll
    for (int mi = 0; mi < 4; ++mi)
      af[mi] = *(const short8*)&Als[((wr << 6) + (mi << 4) + l15) * 32 + (l4 << 3)];
#pragma unroll
    for (int ni = 0; ni < 4; ++ni)
      bfr[ni] = *(const short8*)&Bls[((wc << 6) + (ni << 4) + l15) * 32 + (l4 << 3)];
#pragma unroll
    for (int mi = 0; mi < 4; ++mi)
#pragma unroll
      for (int ni = 0; ni < 4; ++ni)
        acc[mi][ni] = __builtin_amdgcn_mfma_f32_16x16x32_bf16(af[mi], bfr[ni],
                                                              acc[mi][ni], 0, 0, 0);
  }
#pragma unroll
  for (int mi = 0; mi < 4; ++mi) {
#pragma unroll
    for (int ni = 0; ni < 4; ++ni) {
#pragma unroll
      for (int r = 0; r < 4; ++r) {
        int row = bm0 + (wr << 6) + (mi << 4) + (l4 << 2) + r;
        int col = bn0 + (wc << 6) + (ni << 4) + l15;
        float v = acc[mi][ni][r];
        if (MODE == 0) {
          outB[(size_t)row * N + col] = f2bf(v);
        } else if (MODE == 1) {
          int hv = col >> 7;   // 0..7 = K heads, 8..15 = V heads
          int d = col & 127;
          int h = hv & 7;
          if (hv < 8) {
            size_t idx = ((size_t)h * T_LEN + (CACHE_LEN + row)) * HD + d;
            outF[idx] = v;
            outB[idx] = f2bf(v);
          } else {
            size_t idxF = ((size_t)h * T_LEN + (CACHE_LEN + row)) * HD + d + KV_ELEMS;
            outF[idxF] = v;
            outB2[((size_t)h * HD + d) * T_LEN + (CACHE_LEN + row)] = f2bf(v);
          }
        } else {
          outF[(size_t)row * N + col] = v;
        }
      }
    }
  }
}

// ---------------------------------------------------------------------------
// Flash attention v2: block = (q-tile of 64) x (head). 4 waves, 16 q-rows each.
// KVBLK=64. K [64][128] and V^T [128][64] double-buffered in LDS via
// global_load_lds (linear dest, XOR-swizzled global source; reads apply the
// same XOR -> ~2-way banks). Prefetch tile t+1 during compute of tile t.
__global__ __launch_bounds__(256) void attn_fwd(
    const u16* __restrict__ Qb, const u16* __restrict__ Kb,
    const u16* __restrict__ VbT, u16* __restrict__ resB) {
  __shared__ __align__(16) u16 Kls[2][64 * 128];
  __shared__ __align__(16) u16 Vls[2][128 * 64];
  __shared__ __align__(16) u16 Pls[4][16][72];
  const int tid = threadIdx.x;
  const int lane = tid & 63;
  const int wave = tid >> 6;
  const int l15 = lane & 15, l4 = lane >> 4;
  const int hq = blockIdx.y;
  const int kvh = hq & 7;              // reference maps head hq -> kv head hq % 8
  const int bx = (hq & 1) ? (31 - (int)blockIdx.x) : (int)blockIdx.x;  // zigzag balance
  const int q0 = bx << 6;
  const int qw = q0 + (wave << 4);

  // Q fragments in registers for the whole kernel
  short8 aq[4];
  const u16* qrow = Qb + (size_t)(qw + l15) * E_DIM + hq * HD;
#pragma unroll
  for (int kd = 0; kd < 4; ++kd)
    aq[kd] = *(const short8*)(qrow + (kd << 5) + (l4 << 3));

  f32x4 accO[8];
  float mrow[4], lrow[4];
#pragma unroll
  for (int nd = 0; nd < 8; ++nd) {
    accO[nd][0] = 0.f; accO[nd][1] = 0.f; accO[nd][2] = 0.f; accO[nd][3] = 0.f;
  }
#pragma unroll
  for (int r = 0; r < 4; ++r) { mrow[r] = -1e30f; lrow[r] = 0.f; }

  const u16* Kh = Kb + (size_t)kvh * T_LEN * HD;
  const u16* VTh = VbT + (size_t)kvh * (size_t)HD * T_LEN;
  const int nt = bx + 17;              // tiles of 64; nt*64 = q0+1088

  // staging: 4 gl_lds16 per thread per operand; chunk c=(wave*4+s)*64+lane
#define STAGE_TILE(T0, BUF)                                                   \
  {                                                                           \
    _Pragma("unroll")                                                         \
    for (int s = 0; s < 4; ++s) {                                             \
      int tr = (wave << 4) + (s << 2) + (lane >> 4);                          \
      int jd = (lane & 15) ^ (tr & 7);                                        \
      gl_lds16(Kh + (size_t)((T0) + tr) * HD + (jd << 3),                     \
               &Kls[BUF][((wave << 2) + s) << 9]);                            \
      int dr = (wave << 5) + (s << 3) + (lane >> 3);                          \
      int tj = (lane & 7) ^ (dr & 7);                                         \
      gl_lds16(VTh + (size_t)dr * T_LEN + (T0) + (tj << 3),                   \
               &Vls[BUF][((wave << 2) + s) << 9]);                            \
    }                                                                         \
  }

  STAGE_TILE(0, 0);
  __syncthreads();   // vmcnt(0) drain: tile 0 resident

  const float scale = 0.08838834764831845f;  // 1/sqrt(128)
  const int xr = (l15 & 7) << 3;             // read-side XOR (elem units)

  for (int it = 0; it < nt; ++it) {
    const int cur = it & 1;
    const int t0 = it << 6;
    if (it + 1 < nt) STAGE_TILE(t0 + 64, cur ^ 1);

    const u16* Kc = &Kls[cur][0];
    const u16* Vc = &Vls[cur][0];

    // QK^T: 4 col-tiles of 16 kv each, contracting d=128 in 4 chunks
    float p[4][4];
#pragma unroll
    for (int ct = 0; ct < 4; ++ct) {
      f32x4 sc;
      sc[0] = 0.f; sc[1] = 0.f; sc[2] = 0.f; sc[3] = 0.f;
#pragma unroll
      for (int kd = 0; kd < 4; ++kd) {
        short8 bk = *(const short8*)&Kc[((ct << 4) + l15) * 128 +
                                        (((kd << 5) + (l4 << 3)) ^ xr)];
        sc = __builtin_amdgcn_mfma_f32_16x16x32_bf16(aq[kd], bk, sc, 0, 0, 0);
      }
#pragma unroll
      for (int r = 0; r < 4; ++r) p[ct][r] = sc[r] * scale;
    }

    const bool need_mask = (t0 + 63) > (q0 + CACHE_LEN);
    if (need_mask) {
#pragma unroll
      for (int ct = 0; ct < 4; ++ct)
#pragma unroll
        for (int r = 0; r < 4; ++r) {
          int qq = qw + (l4 << 2) + r + CACHE_LEN;
          if (t0 + (ct << 4) + l15 > qq) p[ct][r] = -1e30f;
        }
    }

    // online softmax per q-row (stats replicated across the 16-lane group)
#pragma unroll
    for (int r = 0; r < 4; ++r) {
      float mx = fmaxf(fmaxf(p[0][r], p[1][r]), fmaxf(p[2][r], p[3][r]));
      mx = fmaxf(mx, __shfl_xor(mx, 1));
      mx = fmaxf(mx, __shfl_xor(mx, 2));
      mx = fmaxf(mx, __shfl_xor(mx, 4));
      mx = fmaxf(mx, __shfl_xor(mx, 8));
      float mn = fmaxf(mrow[r], mx);
      float corr = __expf(mrow[r] - mn);
      mrow[r] = mn;
      float rs = 0.f;
#pragma unroll
      for (int ct = 0; ct < 4; ++ct) {
        p[ct][r] = __expf(p[ct][r] - mn);
        rs += p[ct][r];
      }
      rs += __shfl_xor(rs, 1);
      rs += __shfl_xor(rs, 2);
      rs += __shfl_xor(rs, 4);
      rs += __shfl_xor(rs, 8);
      lrow[r] = lrow[r] * corr + rs;
#pragma unroll
      for (int nd = 0; nd < 8; ++nd) accO[nd][r] *= corr;
    }

    // P (D-layout) -> wave-private LDS -> A-fragment layout
#pragma unroll
    for (int ct = 0; ct < 4; ++ct)
#pragma unroll
      for (int r = 0; r < 4; ++r)
        Pls[wave][(l4 << 2) + r][(ct << 4) + l15] = f2bf(p[ct][r]);
    short8 pa0 = *(const short8*)&Pls[wave][l15][l4 << 3];
    short8 pa1 = *(const short8*)&Pls[wave][l15][32 + (l4 << 3)];

    // PV: O[q][d] += P[q][t] * V[t][d]; B-fragment contiguous from V^T rows
#pragma unroll
    for (int nd = 0; nd < 8; ++nd) {
      short8 bv0 = *(const short8*)&Vc[((nd << 4) + l15) * 64 + ((l4 << 3) ^ xr)];
      accO[nd] = __builtin_amdgcn_mfma_f32_16x16x32_bf16(pa0, bv0, accO[nd], 0, 0, 0);
      short8 bv1 = *(const short8*)&Vc[((nd << 4) + l15) * 64 + ((32 + (l4 << 3)) ^ xr)];
      accO[nd] = __builtin_amdgcn_mfma_f32_16x16x32_bf16(pa1, bv1, accO[nd], 0, 0, 0);
    }
    __syncthreads();   // drains prefetch (vmcnt) + LDS reads before overwrite
  }
#undef STAGE_TILE

#pragma unroll
  for (int nd = 0; nd < 8; ++nd) {
#pragma unroll
    for (int r = 0; r < 4; ++r) {
      float v = accO[nd][r] / lrow[r];
      int q = qw + (l4 << 2) + r;
      int d = (nd << 4) + l15;
      resB[(size_t)q * E_DIM + hq * HD + d] = f2bf(v);
    }
  }
}

// ---------------------------------------------------------------------------
extern "C" void kernel_launch(void* const* d_in, const int* in_sizes, int n_in,
                              void* d_out, int out_size, void* d_ws, size_t ws_size,
                              hipStream_t stream) {
  const float* x = (const float*)d_in[0];
  const float* w_q = (const float*)d_in[1];
  const float* w_k = (const float*)d_in[2];
  const float* w_v = (const float*)d_in[3];
  const float* w_o = (const float*)d_in[4];
  const float* k_cache = (const float*)d_in[5];
  const float* v_cache = (const float*)d_in[6];
  // d_in[7] = attention_mask: causal-with-offset; applied analytically.

  float* out = (float*)d_out;                          // [2048][4096]
  float* Kout = out + (size_t)S_LEN * E_DIM;           // [8][3072][128]

  // workspace layout (96 MiB):
  //   [ 0,16)  xb (x bf16) -> reused as resB   [16,32) Qb
  //   [32,38)  Kb  [8][3072][128]              [38,44) VbT [8][128][3072]
  //   [48,64)  wkvt (w_k^T | w_v^T)            [64,96) wbig (w_q^T, then w_o^T)
  char* ws = (char*)d_ws;
  const size_t MB = 1024 * 1024;
  u16* xb   = (u16*)(ws);
  u16* resB = (u16*)(ws);
  u16* Qb   = (u16*)(ws + 16 * MB);
  u16* Kb   = (u16*)(ws + 32 * MB);
  u16* VbT  = (u16*)(ws + 38 * MB);
  u16* wkvt = (u16*)(ws + 48 * MB);
  u16* wbig = (u16*)(ws + 64 * MB);

  cvt_x<<<dim3(8192), dim3(256), 0, stream>>>(x, xb);
  copy_caches<<<dim3(1024), dim3(256), 0, stream>>>(
      (const float4*)k_cache, (const float4*)v_cache,
      (float4*)Kout, (float4*)(Kout + KV_ELEMS), (uint2*)Kb);
  cvt_vcT<<<dim3(16, 2, 8), dim3(256), 0, stream>>>(v_cache, VbT);
  cvt_wt<<<dim3(1024), dim3(256), 0, stream>>>(w_k, wkvt, E_DIM, NHKV * HD);
  cvt_wt<<<dim3(1024), dim3(256), 0, stream>>>(w_v, wkvt + (size_t)1024 * E_DIM, E_DIM, NHKV * HD);
  cvt_wt<<<dim3(4096), dim3(256), 0, stream>>>(w_q, wbig, E_DIM, E_DIM);
  gemm2<1><<<dim3(16 * 16), dim3(256), 0, stream>>>(xb, wkvt, S_LEN, 2048, E_DIM, Kout, Kb, VbT);
  gemm2<0><<<dim3(16 * 32), dim3(256), 0, stream>>>(xb, wbig, S_LEN, E_DIM, E_DIM, nullptr, Qb, nullptr);
  cvt_wt<<<dim3(4096), dim3(256), 0, stream>>>(w_o, wbig, E_DIM, E_DIM);
  attn_fwd<<<dim3(32, 32), dim3(256), 0, stream>>>(Qb, Kb, VbT, resB);
  gemm2<2><<<dim3(16 * 32), dim3(256), 0, stream>>>(resB, wbig, S_LEN, E_DIM, E_DIM, out, nullptr, nullptr);
}

// Round 9
// 754.765 us; speedup vs baseline: 1.6716x; 1.0509x over previous
//
#include <hip/hip_runtime.h>

typedef unsigned short u16;
typedef unsigned int u32;
typedef __attribute__((ext_vector_type(8))) short short8;
typedef __attribute__((ext_vector_type(4))) float f32x4;

#define S_LEN 2048
#define E_DIM 4096
#define NHQ 32
#define NHKV 8
#define HD 128
#define CACHE_LEN 1024
#define T_LEN 3072
#define KV_ELEMS ((size_t)NHKV * T_LEN * HD)   // 3145728

__device__ __forceinline__ u16 f2bf(float f) {
  union { float f; u32 u; } v; v.f = f;
  u32 u = v.u;
  return (u16)((u + 0x7FFFu + ((u >> 16) & 1u)) >> 16);
}

// global -> LDS direct copy, 16 bytes per lane (wave-uniform LDS base, HW adds lane*16)
__device__ __forceinline__ void gl_lds16(const void* g, void* l) {
  __builtin_amdgcn_global_load_lds(
      (const __attribute__((address_space(1))) unsigned int*)g,
      (__attribute__((address_space(3))) unsigned int*)l, 16, 0, 0);
}

// ---------------------------------------------------------------------------
// x (fp32) -> bf16
__global__ __launch_bounds__(256) void cvt_x(const float* __restrict__ x,
                                             u16* __restrict__ xb) {
  int i = blockIdx.x * 256 + threadIdx.x;
  float4 v = ((const float4*)x)[i];
  uint2 o;
  o.x = (u32)f2bf(v.x) | ((u32)f2bf(v.y) << 16);
  o.y = (u32)f2bf(v.z) | ((u32)f2bf(v.w) << 16);
  ((uint2*)xb)[i] = o;
}

// ---------------------------------------------------------------------------
// caches: fp32 copy into d_out K/V regions (t < 1024) + K bf16 shadow (row-major)
__global__ __launch_bounds__(256) void copy_caches(
    const float4* __restrict__ kc, const float4* __restrict__ vc,
    float4* __restrict__ Ko, float4* __restrict__ Vo,
    uint2* __restrict__ Kb) {
  int i = blockIdx.x * 256 + threadIdx.x;  // 262144 float4
  int h = i >> 15;
  size_t o = (size_t)i + ((size_t)h << 16);
  float4 v = kc[i];
  Ko[o] = v;
  uint2 b;
  b.x = (u32)f2bf(v.x) | ((u32)f2bf(v.y) << 16);
  b.y = (u32)f2bf(v.z) | ((u32)f2bf(v.w) << 16);
  Kb[o] = b;
  Vo[o] = vc[i];
}

// ---------------------------------------------------------------------------
// v_cache fp32 [h][1024][128] -> V^T bf16 [h][128][3072] (cols 0..1023), LDS-tiled
__global__ __launch_bounds__(256) void cvt_vcT(const float* __restrict__ vc,
                                               u16* __restrict__ vbT) {
  __shared__ u16 t[64][68];
  const int tid = threadIdx.x;
  const int h = blockIdx.z;
  const int t0 = blockIdx.x << 6;   // 16 t-tiles
  const int d0 = blockIdx.y << 6;   // 2 d-tiles
  const float* in = vc + ((size_t)h * CACHE_LEN + t0) * HD + d0;
  const int rl = tid >> 4;
  const int c4 = (tid & 15) << 2;
#pragma unroll
  for (int i = 0; i < 4; ++i) {
    int rr = rl + (i << 4);
    float4 v = *(const float4*)&in[(size_t)rr * HD + c4];
    t[c4 + 0][rr] = f2bf(v.x);
    t[c4 + 1][rr] = f2bf(v.y);
    t[c4 + 2][rr] = f2bf(v.z);
    t[c4 + 3][rr] = f2bf(v.w);
  }
  __syncthreads();
  u16* outp = vbT + ((size_t)h * HD + d0) * T_LEN + t0;
#pragma unroll
  for (int p = 0; p < 2; ++p) {
    int idx = tid + (p << 8);
    int dr = idx >> 3;
    int ch = (idx & 7) << 3;
    u32 a0 = (u32)t[dr][ch + 0] | ((u32)t[dr][ch + 1] << 16);
    u32 a1 = (u32)t[dr][ch + 2] | ((u32)t[dr][ch + 3] << 16);
    u32 a2 = (u32)t[dr][ch + 4] | ((u32)t[dr][ch + 5] << 16);
    u32 a3 = (u32)t[dr][ch + 6] | ((u32)t[dr][ch + 7] << 16);
    uint4 o4; o4.x = a0; o4.y = a1; o4.z = a2; o4.w = a3;
    *(uint4*)&outp[(size_t)dr * T_LEN + ch] = o4;
  }
}

// ---------------------------------------------------------------------------
// weight transpose + convert: w fp32 [K][N] -> wt bf16 [N][K]. 64x64 tiles.
__global__ __launch_bounds__(256) void cvt_wt(const float* __restrict__ w,
                                              u16* __restrict__ wt,
                                              int K, int N) {
  __shared__ u16 t[64][68];
  const int tid = threadIdx.x;
  const int ntk = K >> 6;
  const int k0 = (blockIdx.x % ntk) << 6;
  const int n0 = (blockIdx.x / ntk) << 6;
  const int kl = tid >> 4;
  const int nl4 = (tid & 15) << 2;
#pragma unroll
  for (int i = 0; i < 4; ++i) {
    int kk = kl + (i << 4);
    float4 v = *(const float4*)&w[(size_t)(k0 + kk) * N + n0 + nl4];
    t[nl4 + 0][kk] = f2bf(v.x);
    t[nl4 + 1][kk] = f2bf(v.y);
    t[nl4 + 2][kk] = f2bf(v.z);
    t[nl4 + 3][kk] = f2bf(v.w);
  }
  __syncthreads();
  const int onl = tid >> 3;
  const int okc = (tid & 7) << 3;
#pragma unroll
  for (int p = 0; p < 2; ++p) {
    int nl = onl + (p << 5);
    u32 a0 = (u32)t[nl][okc + 0] | ((u32)t[nl][okc + 1] << 16);
    u32 a1 = (u32)t[nl][okc + 2] | ((u32)t[nl][okc + 3] << 16);
    u32 a2 = (u32)t[nl][okc + 4] | ((u32)t[nl][okc + 5] << 16);
    u32 a3 = (u32)t[nl][okc + 6] | ((u32)t[nl][okc + 7] << 16);
    uint4 o4; o4.x = a0; o4.y = a1; o4.z = a2; o4.w = a3;
    *(uint4*)&wt[(size_t)(n0 + nl) * K + k0 + okc] = o4;
  }
}

// ---------------------------------------------------------------------------
// m97-structure GEMM: C[M,N] = A[M,K](bf16) * Bt[N,K](bf16)^T
// MODE 0: bf16 -> outB[M][N]                   (Q projection)
// MODE 1: fp32 + shadows -> K/V concat slots   (fused KV projection, N=2048;
//          K shadow row-major in outB, V shadow transposed in outB2)
// MODE 2: fp32 -> outF[M][N]                   (output projection)
template<int MODE>
__global__ __launch_bounds__(256) void gemm2(
    const u16* __restrict__ A, const u16* __restrict__ Bt,
    int M, int N, int K,
    float* __restrict__ outF, u16* __restrict__ outB, u16* __restrict__ outB2) {
  __shared__ __align__(16) u16 Als[128 * 32];
  __shared__ __align__(16) u16 Bls[128 * 32];
  const int tid = threadIdx.x;
  const int lane = tid & 63;
  const int wave = tid >> 6;
  const int wr = wave >> 1, wc = wave & 1;
  const int l15 = lane & 15, l4 = lane >> 4;
  const int nbn = N >> 7;
  const int bm0 = (blockIdx.x / nbn) << 7;
  const int bn0 = (blockIdx.x % nbn) << 7;

  f32x4 acc[4][4];
#pragma unroll
  for (int i = 0; i < 4; ++i)
#pragma unroll
    for (int j = 0; j < 4; ++j) {
      acc[i][j][0] = 0.f; acc[i][j][1] = 0.f;
      acc[i][j][2] = 0.f; acc[i][j][3] = 0.f;
    }

  const u16* Abase = A + (size_t)bm0 * K;
  const u16* Bbase = Bt + (size_t)bn0 * K;
  const int c0 = tid, c1 = tid + 256;
  const int r0 = c0 >> 2, q0c = (c0 & 3) << 3;
  const int r1 = c1 >> 2, q1c = (c1 & 3) << 3;

  for (int k0 = 0; k0 < K; k0 += 32) {
    __syncthreads();
    gl_lds16(Abase + (size_t)r0 * K + k0 + q0c, &Als[c0 << 3]);
    gl_lds16(Bbase + (size_t)r0 * K + k0 + q0c, &Bls[c0 << 3]);
    gl_lds16(Abase + (size_t)r1 * K + k0 + q1c, &Als[c1 << 3]);
    gl_lds16(Bbase + (size_t)r1 * K + k0 + q1c, &Bls[c1 << 3]);
    __syncthreads();

    short8 af[4], bfr[4];
#pragma unroll
    for (int mi = 0; mi < 4; ++mi)
      af[mi] = *(const short8*)&Als[((wr << 6) + (mi << 4) + l15) * 32 + (l4 << 3)];
#pragma unroll
    for (int ni = 0; ni < 4; ++ni)
      bfr[ni] = *(const short8*)&Bls[((wc << 6) + (ni << 4) + l15) * 32 + (l4 << 3)];
#pragma unroll
    for (int mi = 0; mi < 4; ++mi)
#pragma unroll
      for (int ni = 0; ni < 4; ++ni)
        acc[mi][ni] = __builtin_amdgcn_mfma_f32_16x16x32_bf16(af[mi], bfr[ni],
                                                              acc[mi][ni], 0, 0, 0);
  }
#pragma unroll
  for (int mi = 0; mi < 4; ++mi) {
#pragma unroll
    for (int ni = 0; ni < 4; ++ni) {
#pragma unroll
      for (int r = 0; r < 4; ++r) {
        int row = bm0 + (wr << 6) + (mi << 4) + (l4 << 2) + r;
        int col = bn0 + (wc << 6) + (ni << 4) + l15;
        float v = acc[mi][ni][r];
        if (MODE == 0) {
          outB[(size_t)row * N + col] = f2bf(v);
        } else if (MODE == 1) {
          int hv = col >> 7;   // 0..7 = K heads, 8..15 = V heads
          int d = col & 127;
          int h = hv & 7;
          if (hv < 8) {
            size_t idx = ((size_t)h * T_LEN + (CACHE_LEN + row)) * HD + d;
            outF[idx] = v;
            outB[idx] = f2bf(v);
          } else {
            size_t idxF = ((size_t)h * T_LEN + (CACHE_LEN + row)) * HD + d + KV_ELEMS;
            outF[idxF] = v;
            outB2[((size_t)h * HD + d) * T_LEN + (CACHE_LEN + row)] = f2bf(v);
          }
        } else {
          outF[(size_t)row * N + col] = v;
        }
      }
    }
  }
}

// ---------------------------------------------------------------------------
// Flash attention v3: QBLK=256 (8 waves x 32 q-rows), KVBLK=64, dbuf LDS K/V^T
// via global_load_lds with both-sides XOR swizzle. Grid = 256 blocks,
// bid = bx*32 + hq  ->  XCD = bid%8 = kvh: each XCD's L2 holds exactly one
// kv-head's K+V (3.1 MB < 4 MB) -> KV reads are L2-resident.
// Defer-max (T13, THR=8): wave-voted skip of the per-tile O-rescale.
__global__ __launch_bounds__(512, 2) void attn_fwd(
    const u16* __restrict__ Qb, const u16* __restrict__ Kb,
    const u16* __restrict__ VbT, u16* __restrict__ resB) {
  __shared__ __align__(16) u16 Kls[2][64 * 128];
  __shared__ __align__(16) u16 Vls[2][128 * 64];
  __shared__ __align__(16) u16 Pls[8][16][72];
  const int tid = threadIdx.x;
  const int lane = tid & 63;
  const int wave = tid >> 6;             // 0..7
  const int l15 = lane & 15, l4 = lane >> 4;
  const int bid = blockIdx.x;
  const int hq = bid & 31;
  const int bx = bid >> 5;               // 0..7
  const int kvh = hq & 7;                // reference: query head hq -> kv head hq % 8
  const int q0 = bx << 8;                // 256 q-rows per block
  const int qw = q0 + (wave << 5);       // 32 rows per wave (2 rowgroups of 16)

  // Q fragments in registers for the whole kernel: aq[rg][kd]
  short8 aq[2][4];
#pragma unroll
  for (int rg = 0; rg < 2; ++rg) {
    const u16* qrow = Qb + (size_t)(qw + (rg << 4) + l15) * E_DIM + hq * HD;
#pragma unroll
    for (int kd = 0; kd < 4; ++kd)
      aq[rg][kd] = *(const short8*)(qrow + (kd << 5) + (l4 << 3));
  }

  f32x4 accO[2][8];
  float mrow[2][4], lrow[2][4];
#pragma unroll
  for (int rg = 0; rg < 2; ++rg) {
#pragma unroll
    for (int nd = 0; nd < 8; ++nd) {
      accO[rg][nd][0] = 0.f; accO[rg][nd][1] = 0.f;
      accO[rg][nd][2] = 0.f; accO[rg][nd][3] = 0.f;
    }
#pragma unroll
    for (int r = 0; r < 4; ++r) { mrow[rg][r] = -1e30f; lrow[rg][r] = 0.f; }
  }

  const u16* Kh = Kb + (size_t)kvh * T_LEN * HD;
  const u16* VTh = VbT + (size_t)kvh * (size_t)HD * T_LEN;
  const int nt = (bx << 2) + 20;         // tiles of 64; nt*64 = q0+1280

  // staging pointers (tile-invariant swizzle; advance by constant per tile)
  const int trk = (wave << 3) + (lane >> 4);           // K rows, s=0
  const int jd0 = (lane & 15) ^ (trk & 7);
  const int jd1 = (lane & 15) ^ ((trk + 4) & 7);
  const u16* kp0 = Kh + (size_t)trk * HD + (jd0 << 3);
  const u16* kp1 = Kh + (size_t)(trk + 4) * HD + (jd1 << 3);
  const int drv = (wave << 4) + (lane >> 3);           // V^T rows, s=0
  const int tj0 = (lane & 7) ^ (drv & 7);              // (drv+8)&7 == drv&7
  const u16* vp0 = VTh + (size_t)drv * T_LEN + (tj0 << 3);
  const u16* vp1 = VTh + (size_t)(drv + 8) * T_LEN + (tj0 << 3);

#define STAGE(BUF)                                             \
  {                                                            \
    gl_lds16(kp0, &Kls[BUF][((wave << 1) + 0) << 9]);          \
    gl_lds16(kp1, &Kls[BUF][((wave << 1) + 1) << 9]);          \
    gl_lds16(vp0, &Vls[BUF][((wave << 1) + 0) << 9]);          \
    gl_lds16(vp1, &Vls[BUF][((wave << 1) + 1) << 9]);          \
    kp0 += 64 * HD; kp1 += 64 * HD; vp0 += 64; vp1 += 64;      \
  }

  STAGE(0);
  __syncthreads();   // vmcnt(0) drain: tile 0 resident

  const float scale = 0.08838834764831845f;  // 1/sqrt(128)
  const int xr = (l15 & 7) << 3;             // read-side XOR (elem units)

  for (int it = 0; it < nt; ++it) {
    const int cur = it & 1;
    const int t0 = it << 6;
    if (it + 1 < nt) STAGE(cur ^ 1);

    const u16* Kc = &Kls[cur][0];
    const u16* Vc = &Vls[cur][0];

#pragma unroll
    for (int rg = 0; rg < 2; ++rg) {
      const int qrg = qw + (rg << 4);
      // QK^T: 4 col-tiles of 16 kv, contracting d=128 in 4 chunks
      float p[4][4];
#pragma unroll
      for (int ct = 0; ct < 4; ++ct) {
        f32x4 sc;
        sc[0] = 0.f; sc[1] = 0.f; sc[2] = 0.f; sc[3] = 0.f;
#pragma unroll
        for (int kd = 0; kd < 4; ++kd) {
          short8 bk = *(const short8*)&Kc[((ct << 4) + l15) * 128 +
                                          (((kd << 5) + (l4 << 3)) ^ xr)];
          sc = __builtin_amdgcn_mfma_f32_16x16x32_bf16(aq[rg][kd], bk, sc, 0, 0, 0);
        }
#pragma unroll
        for (int r = 0; r < 4; ++r) p[ct][r] = sc[r] * scale;
      }

      if ((t0 + 63) > (qrg + CACHE_LEN)) {
#pragma unroll
        for (int ct = 0; ct < 4; ++ct)
#pragma unroll
          for (int r = 0; r < 4; ++r) {
            int qq = qrg + (l4 << 2) + r + CACHE_LEN;
            if (t0 + (ct << 4) + l15 > qq) p[ct][r] = -1e30f;
          }
      }

      // tile max per q-row (replicated across the 16-lane group)
      float mx[4];
#pragma unroll
      for (int r = 0; r < 4; ++r) {
        float m = fmaxf(fmaxf(p[0][r], p[1][r]), fmaxf(p[2][r], p[3][r]));
        m = fmaxf(m, __shfl_xor(m, 1));
        m = fmaxf(m, __shfl_xor(m, 2));
        m = fmaxf(m, __shfl_xor(m, 4));
        m = fmaxf(m, __shfl_xor(m, 8));
        mx[r] = m;
      }
      // defer-max: rescale only when some row's max grew past THR=8
      bool grow = false;
#pragma unroll
      for (int r = 0; r < 4; ++r) grow = grow || (mx[r] > mrow[rg][r] + 8.f);
      if (__any(grow)) {
#pragma unroll
        for (int r = 0; r < 4; ++r) {
          float mn = fmaxf(mrow[rg][r], mx[r]);
          float corr = __expf(mrow[rg][r] - mn);
          mrow[rg][r] = mn;
          lrow[rg][r] *= corr;
#pragma unroll
          for (int nd = 0; nd < 8; ++nd) accO[rg][nd][r] *= corr;
        }
      }
#pragma unroll
      for (int r = 0; r < 4; ++r) {
        float rs = 0.f;
#pragma unroll
        for (int ct = 0; ct < 4; ++ct) {
          p[ct][r] = __expf(p[ct][r] - mrow[rg][r]);
          rs += p[ct][r];
        }
        rs += __shfl_xor(rs, 1);
        rs += __shfl_xor(rs, 2);
        rs += __shfl_xor(rs, 4);
        rs += __shfl_xor(rs, 8);
        lrow[rg][r] += rs;
      }

      // P (D-layout) -> wave-private LDS -> A-fragment layout
#pragma unroll
      for (int ct = 0; ct < 4; ++ct)
#pragma unroll
        for (int r = 0; r < 4; ++r)
          Pls[wave][(l4 << 2) + r][(ct << 4) + l15] = f2bf(p[ct][r]);
      short8 pa0 = *(const short8*)&Pls[wave][l15][l4 << 3];
      short8 pa1 = *(const short8*)&Pls[wave][l15][32 + (l4 << 3)];

      // PV: O[q][d] += P[q][t] * V[t][d]; B-fragment contiguous from V^T rows
#pragma unroll
      for (int nd = 0; nd < 8; ++nd) {
        short8 bv0 = *(const short8*)&Vc[((nd << 4) + l15) * 64 + ((l4 << 3) ^ xr)];
        accO[rg][nd] = __builtin_amdgcn_mfma_f32_16x16x32_bf16(pa0, bv0, accO[rg][nd], 0, 0, 0);
        short8 bv1 = *(const short8*)&Vc[((nd << 4) + l15) * 64 + ((32 + (l4 << 3)) ^ xr)];
        accO[rg][nd] = __builtin_amdgcn_mfma_f32_16x16x32_bf16(pa1, bv1, accO[rg][nd], 0, 0, 0);
      }
    }
    __syncthreads();   // drains prefetch (vmcnt) + LDS reads before overwrite
  }
#undef STAGE

#pragma unroll
  for (int rg = 0; rg < 2; ++rg) {
    float inv[4];
#pragma unroll
    for (int r = 0; r < 4; ++r) inv[r] = 1.0f / lrow[rg][r];
#pragma unroll
    for (int nd = 0; nd < 8; ++nd) {
#pragma unroll
      for (int r = 0; r < 4; ++r) {
        float v = accO[rg][nd][r] * inv[r];
        int q = qw + (rg << 4) + (l4 << 2) + r;
        int d = (nd << 4) + l15;
        resB[(size_t)q * E_DIM + hq * HD + d] = f2bf(v);
      }
    }
  }
}

// ---------------------------------------------------------------------------
extern "C" void kernel_launch(void* const* d_in, const int* in_sizes, int n_in,
                              void* d_out, int out_size, void* d_ws, size_t ws_size,
                              hipStream_t stream) {
  const float* x = (const float*)d_in[0];
  const float* w_q = (const float*)d_in[1];
  const float* w_k = (const float*)d_in[2];
  const float* w_v = (const float*)d_in[3];
  const float* w_o = (const float*)d_in[4];
  const float* k_cache = (const float*)d_in[5];
  const float* v_cache = (const float*)d_in[6];
  // d_in[7] = attention_mask: causal-with-offset; applied analytically.

  float* out = (float*)d_out;                          // [2048][4096]
  float* Kout = out + (size_t)S_LEN * E_DIM;           // [8][3072][128]

  // workspace layout (96 MiB):
  //   [ 0,16)  xb (x bf16) -> reused as resB   [16,32) Qb
  //   [32,38)  Kb  [8][3072][128]              [38,44) VbT [8][128][3072]
  //   [48,64)  wkvt (w_k^T | w_v^T)            [64,96) wbig (w_q^T, then w_o^T)
  char* ws = (char*)d_ws;
  const size_t MB = 1024 * 1024;
  u16* xb   = (u16*)(ws);
  u16* resB = (u16*)(ws);
  u16* Qb   = (u16*)(ws + 16 * MB);
  u16* Kb   = (u16*)(ws + 32 * MB);
  u16* VbT  = (u16*)(ws + 38 * MB);
  u16* wkvt = (u16*)(ws + 48 * MB);
  u16* wbig = (u16*)(ws + 64 * MB);

  cvt_x<<<dim3(8192), dim3(256), 0, stream>>>(x, xb);
  copy_caches<<<dim3(1024), dim3(256), 0, stream>>>(
      (const float4*)k_cache, (const float4*)v_cache,
      (float4*)Kout, (float4*)(Kout + KV_ELEMS), (uint2*)Kb);
  cvt_vcT<<<dim3(16, 2, 8), dim3(256), 0, stream>>>(v_cache, VbT);
  cvt_wt<<<dim3(1024), dim3(256), 0, stream>>>(w_k, wkvt, E_DIM, NHKV * HD);
  cvt_wt<<<dim3(1024), dim3(256), 0, stream>>>(w_v, wkvt + (size_t)1024 * E_DIM, E_DIM, NHKV * HD);
  cvt_wt<<<dim3(4096), dim3(256), 0, stream>>>(w_q, wbig, E_DIM, E_DIM);
  gemm2<1><<<dim3(16 * 16), dim3(256), 0, stream>>>(xb, wkvt, S_LEN, 2048, E_DIM, Kout, Kb, VbT);
  gemm2<0><<<dim3(16 * 32), dim3(256), 0, stream>>>(xb, wbig, S_LEN, E_DIM, E_DIM, nullptr, Qb, nullptr);
  cvt_wt<<<dim3(4096), dim3(256), 0, stream>>>(w_o, wbig, E_DIM, E_DIM);
  attn_fwd<<<dim3(256), dim3(512), 0, stream>>>(Qb, Kb, VbT, resB);
  gemm2<2><<<dim3(16 * 32), dim3(256), 0, stream>>>(resB, wbig, S_LEN, E_DIM, E_DIM, out, nullptr, nullptr);
}

// Round 10
// 721.170 us; speedup vs baseline: 1.7495x; 1.0466x over previous
//
#include <hip/hip_runtime.h>

typedef unsigned short u16;
typedef unsigned int u32;
typedef __attribute__((ext_vector_type(8))) short short8;
typedef __attribute__((ext_vector_type(4))) float f32x4;

#define S_LEN 2048
#define E_DIM 4096
#define NHQ 32
#define NHKV 8
#define HD 128
#define CACHE_LEN 1024
#define T_LEN 3072
#define KV_ELEMS ((size_t)NHKV * T_LEN * HD)   // 3145728

__device__ __forceinline__ u16 f2bf(float f) {
  union { float f; u32 u; } v; v.f = f;
  u32 u = v.u;
  return (u16)((u + 0x7FFFu + ((u >> 16) & 1u)) >> 16);
}

// global -> LDS direct copy, 16 bytes per lane (wave-uniform LDS base, HW adds lane*16)
__device__ __forceinline__ void gl_lds16(const void* g, void* l) {
  __builtin_amdgcn_global_load_lds(
      (const __attribute__((address_space(1))) unsigned int*)g,
      (__attribute__((address_space(3))) unsigned int*)l, 16, 0, 0);
}

// ---------------------------------------------------------------------------
// x (fp32) -> bf16
__global__ __launch_bounds__(256) void cvt_x(const float* __restrict__ x,
                                             u16* __restrict__ xb) {
  int i = blockIdx.x * 256 + threadIdx.x;
  float4 v = ((const float4*)x)[i];
  uint2 o;
  o.x = (u32)f2bf(v.x) | ((u32)f2bf(v.y) << 16);
  o.y = (u32)f2bf(v.z) | ((u32)f2bf(v.w) << 16);
  ((uint2*)xb)[i] = o;
}

// ---------------------------------------------------------------------------
// caches: fp32 copy into d_out K/V regions (t < 1024) + K bf16 shadow (row-major)
__global__ __launch_bounds__(256) void copy_caches(
    const float4* __restrict__ kc, const float4* __restrict__ vc,
    float4* __restrict__ Ko, float4* __restrict__ Vo,
    uint2* __restrict__ Kb) {
  int i = blockIdx.x * 256 + threadIdx.x;  // 262144 float4
  int h = i >> 15;
  size_t o = (size_t)i + ((size_t)h << 16);
  float4 v = kc[i];
  Ko[o] = v;
  uint2 b;
  b.x = (u32)f2bf(v.x) | ((u32)f2bf(v.y) << 16);
  b.y = (u32)f2bf(v.z) | ((u32)f2bf(v.w) << 16);
  Kb[o] = b;
  Vo[o] = vc[i];
}

// ---------------------------------------------------------------------------
// v_cache fp32 [h][1024][128] -> V^T bf16 [h][128][3072] (cols 0..1023), LDS-tiled
__global__ __launch_bounds__(256) void cvt_vcT(const float* __restrict__ vc,
                                               u16* __restrict__ vbT) {
  __shared__ u16 t[64][68];
  const int tid = threadIdx.x;
  const int h = blockIdx.z;
  const int t0 = blockIdx.x << 6;   // 16 t-tiles
  const int d0 = blockIdx.y << 6;   // 2 d-tiles
  const float* in = vc + ((size_t)h * CACHE_LEN + t0) * HD + d0;
  const int rl = tid >> 4;
  const int c4 = (tid & 15) << 2;
#pragma unroll
  for (int i = 0; i < 4; ++i) {
    int rr = rl + (i << 4);
    float4 v = *(const float4*)&in[(size_t)rr * HD + c4];
    t[c4 + 0][rr] = f2bf(v.x);
    t[c4 + 1][rr] = f2bf(v.y);
    t[c4 + 2][rr] = f2bf(v.z);
    t[c4 + 3][rr] = f2bf(v.w);
  }
  __syncthreads();
  u16* outp = vbT + ((size_t)h * HD + d0) * T_LEN + t0;
#pragma unroll
  for (int p = 0; p < 2; ++p) {
    int idx = tid + (p << 8);
    int dr = idx >> 3;
    int ch = (idx & 7) << 3;
    u32 a0 = (u32)t[dr][ch + 0] | ((u32)t[dr][ch + 1] << 16);
    u32 a1 = (u32)t[dr][ch + 2] | ((u32)t[dr][ch + 3] << 16);
    u32 a2 = (u32)t[dr][ch + 4] | ((u32)t[dr][ch + 5] << 16);
    u32 a3 = (u32)t[dr][ch + 6] | ((u32)t[dr][ch + 7] << 16);
    uint4 o4; o4.x = a0; o4.y = a1; o4.z = a2; o4.w = a3;
    *(uint4*)&outp[(size_t)dr * T_LEN + ch] = o4;
  }
}

// ---------------------------------------------------------------------------
// weight transpose + convert: w fp32 [K][N] -> wt bf16 [N][K]. 64x64 tiles.
__global__ __launch_bounds__(256) void cvt_wt(const float* __restrict__ w,
                                              u16* __restrict__ wt,
                                              int K, int N) {
  __shared__ u16 t[64][68];
  const int tid = threadIdx.x;
  const int ntk = K >> 6;
  const int k0 = (blockIdx.x % ntk) << 6;
  const int n0 = (blockIdx.x / ntk) << 6;
  const int kl = tid >> 4;
  const int nl4 = (tid & 15) << 2;
#pragma unroll
  for (int i = 0; i < 4; ++i) {
    int kk = kl + (i << 4);
    float4 v = *(const float4*)&w[(size_t)(k0 + kk) * N + n0 + nl4];
    t[nl4 + 0][kk] = f2bf(v.x);
    t[nl4 + 1][kk] = f2bf(v.y);
    t[nl4 + 2][kk] = f2bf(v.z);
    t[nl4 + 3][kk] = f2bf(v.w);
  }
  __syncthreads();
  const int onl = tid >> 3;
  const int okc = (tid & 7) << 3;
#pragma unroll
  for (int p = 0; p < 2; ++p) {
    int nl = onl + (p << 5);
    u32 a0 = (u32)t[nl][okc + 0] | ((u32)t[nl][okc + 1] << 16);
    u32 a1 = (u32)t[nl][okc + 2] | ((u32)t[nl][okc + 3] << 16);
    u32 a2 = (u32)t[nl][okc + 4] | ((u32)t[nl][okc + 5] << 16);
    u32 a3 = (u32)t[nl][okc + 6] | ((u32)t[nl][okc + 7] << 16);
    uint4 o4; o4.x = a0; o4.y = a1; o4.z = a2; o4.w = a3;
    *(uint4*)&wt[(size_t)(n0 + nl) * K + k0 + okc] = o4;
  }
}

// ---------------------------------------------------------------------------
// m97-structure GEMM: C[M,N] = A[M,K](bf16) * Bt[N,K](bf16)^T
// MODE 0: bf16 -> outB[M][N]                   (Q projection)
// MODE 1: fp32 + shadows -> K/V concat slots   (fused KV projection, N=2048;
//          K shadow row-major in outB, V shadow transposed in outB2)
// MODE 2: fp32 -> outF[M][N]                   (output projection)
template<int MODE>
__global__ __launch_bounds__(256) void gemm2(
    const u16* __restrict__ A, const u16* __restrict__ Bt,
    int M, int N, int K,
    float* __restrict__ outF, u16* __restrict__ outB, u16* __restrict__ outB2) {
  __shared__ __align__(16) u16 Als[128 * 32];
  __shared__ __align__(16) u16 Bls[128 * 32];
  const int tid = threadIdx.x;
  const int lane = tid & 63;
  const int wave = tid >> 6;
  const int wr = wave >> 1, wc = wave & 1;
  const int l15 = lane & 15, l4 = lane >> 4;
  const int nbn = N >> 7;
  const int bm0 = (blockIdx.x / nbn) << 7;
  const int bn0 = (blockIdx.x % nbn) << 7;

  f32x4 acc[4][4];
#pragma unroll
  for (int i = 0; i < 4; ++i)
#pragma unroll
    for (int j = 0; j < 4; ++j) {
      acc[i][j][0] = 0.f; acc[i][j][1] = 0.f;
      acc[i][j][2] = 0.f; acc[i][j][3] = 0.f;
    }

  const u16* Abase = A + (size_t)bm0 * K;
  const u16* Bbase = Bt + (size_t)bn0 * K;
  const int c0 = tid, c1 = tid + 256;
  const int r0 = c0 >> 2, q0c = (c0 & 3) << 3;
  const int r1 = c1 >> 2, q1c = (c1 & 3) << 3;

  for (int k0 = 0; k0 < K; k0 += 32) {
    __syncthreads();
    gl_lds16(Abase + (size_t)r0 * K + k0 + q0c, &Als[c0 << 3]);
    gl_lds16(Bbase + (size_t)r0 * K + k0 + q0c, &Bls[c0 << 3]);
    gl_lds16(Abase + (size_t)r1 * K + k0 + q1c, &Als[c1 << 3]);
    gl_lds16(Bbase + (size_t)r1 * K + k0 + q1c, &Bls[c1 << 3]);
    __syncthreads();

    short8 af[4], bfr[4];
#pragma unroll
    for (int mi = 0; mi < 4; ++mi)
      af[mi] = *(const short8*)&Als[((wr << 6) + (mi << 4) + l15) * 32 + (l4 << 3)];
#pragma unroll
    for (int ni = 0; ni < 4; ++ni)
      bfr[ni] = *(const short8*)&Bls[((wc << 6) + (ni << 4) + l15) * 32 + (l4 << 3)];
#pragma unroll
    for (int mi = 0; mi < 4; ++mi)
#pragma unroll
      for (int ni = 0; ni < 4; ++ni)
        acc[mi][ni] = __builtin_amdgcn_mfma_f32_16x16x32_bf16(af[mi], bfr[ni],
                                                              acc[mi][ni], 0, 0, 0);
  }
#pragma unroll
  for (int mi = 0; mi < 4; ++mi) {
#pragma unroll
    for (int ni = 0; ni < 4; ++ni) {
#pragma unroll
      for (int r = 0; r < 4; ++r) {
        int row = bm0 + (wr << 6) + (mi << 4) + (l4 << 2) + r;
        int col = bn0 + (wc << 6) + (ni << 4) + l15;
        float v = acc[mi][ni][r];
        if (MODE == 0) {
          outB[(size_t)row * N + col] = f2bf(v);
        } else if (MODE == 1) {
          int hv = col >> 7;   // 0..7 = K heads, 8..15 = V heads
          int d = col & 127;
          int h = hv & 7;
          if (hv < 8) {
            size_t idx = ((size_t)h * T_LEN + (CACHE_LEN + row)) * HD + d;
            outF[idx] = v;
            outB[idx] = f2bf(v);
          } else {
            size_t idxF = ((size_t)h * T_LEN + (CACHE_LEN + row)) * HD + d + KV_ELEMS;
            outF[idxF] = v;
            outB2[((size_t)h * HD + d) * T_LEN + (CACHE_LEN + row)] = f2bf(v);
          }
        } else {
          outF[(size_t)row * N + col] = v;
        }
      }
    }
  }
}

// ---------------------------------------------------------------------------
// Flash attention v4: balanced two-phase blocks. 16 q-tiles of 128 rows;
// block p handles q-tile p then q-tile 15-p (total KV tiles = 66, constant ->
// no dispatch tail). 8 waves x 16 q-rows per phase. KVBLK=64, dbuf LDS K/V^T
// via global_load_lds (both-sides XOR swizzle). bid%8 = kvh: per-XCD L2 holds
// one kv-head's K+V (3.1 MB). Softmax in exp2 domain; defer-max THR=11 (log2).
__global__ __launch_bounds__(512, 2) void attn_fwd(
    const u16* __restrict__ Qb, const u16* __restrict__ Kb,
    const u16* __restrict__ VbT, u16* __restrict__ resB) {
  __shared__ __align__(16) u16 Kls[2][64 * 128];
  __shared__ __align__(16) u16 Vls[2][128 * 64];
  __shared__ __align__(16) u16 Pls[8][16][74];   // pitch 74: ~2-way store banks
  const int tid = threadIdx.x;
  const int lane = tid & 63;
  const int wave = tid >> 6;             // 0..7
  const int l15 = lane & 15, l4 = lane >> 4;
  const int bid = blockIdx.x;
  const int hq = bid & 31;
  const int pr = bid >> 5;               // 0..7 (pair index)
  const int kvh = hq & 7;                // reference: query head hq -> kv head hq % 8

  const u16* Kh = Kb + (size_t)kvh * T_LEN * HD;
  const u16* VTh = VbT + (size_t)kvh * (size_t)HD * T_LEN;

  // staging lane geometry (tile-invariant)
  const int trk = (wave << 3) + (lane >> 4);           // K rows, s=0
  const int jd0 = (lane & 15) ^ (trk & 7);
  const int jd1 = (lane & 15) ^ ((trk + 4) & 7);
  const int drv = (wave << 4) + (lane >> 3);           // V^T rows, s=0
  const int tj0 = (lane & 7) ^ (drv & 7);              // (drv+8)&7 == drv&7
  const int xr = (l15 & 7) << 3;                       // read-side XOR (elems)
  const float scale2 = 0.12754245006340912f;           // log2(e)/sqrt(128)

#define STAGE(BUF)                                             \
  {                                                            \
    gl_lds16(kp0, &Kls[BUF][((wave << 1) + 0) << 9]);          \
    gl_lds16(kp1, &Kls[BUF][((wave << 1) + 1) << 9]);          \
    gl_lds16(vp0, &Vls[BUF][((wave << 1) + 0) << 9]);          \
    gl_lds16(vp1, &Vls[BUF][((wave << 1) + 1) << 9]);          \
    kp0 += 64 * HD; kp1 += 64 * HD; vp0 += 64; vp1 += 64;      \
  }

  for (int ph = 0; ph < 2; ++ph) {
    const int qt = ph ? (15 - pr) : pr;  // q-tile index (128 rows)
    const int q0 = qt << 7;
    const int qw = q0 + (wave << 4);     // this wave's 16 q-rows
    const int nt = (qt << 1) + 18;       // KV tiles of 64; nt*64 = q0+1152

    // Q fragments for this phase
    short8 aq[4];
    const u16* qrow = Qb + (size_t)(qw + l15) * E_DIM + hq * HD;
#pragma unroll
    for (int kd = 0; kd < 4; ++kd)
      aq[kd] = *(const short8*)(qrow + (kd << 5) + (l4 << 3));

    f32x4 accO[8];
    float mrow[4], lrow[4];
#pragma unroll
    for (int nd = 0; nd < 8; ++nd) {
      accO[nd][0] = 0.f; accO[nd][1] = 0.f;
      accO[nd][2] = 0.f; accO[nd][3] = 0.f;
    }
#pragma unroll
    for (int r = 0; r < 4; ++r) { mrow[r] = -1e30f; lrow[r] = 0.f; }

    // staging pointers for this phase
    const u16* kp0 = Kh + (size_t)trk * HD + (jd0 << 3);
    const u16* kp1 = Kh + (size_t)(trk + 4) * HD + (jd1 << 3);
    const u16* vp0 = VTh + (size_t)drv * T_LEN + (tj0 << 3);
    const u16* vp1 = VTh + (size_t)(drv + 8) * T_LEN + (tj0 << 3);

    STAGE(0);
    __syncthreads();   // vmcnt(0) drain: tile 0 resident

    for (int it = 0; it < nt; ++it) {
      const int cur = it & 1;
      const int t0 = it << 6;
      if (it + 1 < nt) STAGE(cur ^ 1);

      const u16* Kc = &Kls[cur][0];
      const u16* Vc = &Vls[cur][0];

      // QK^T (log2 domain): 4 col-tiles of 16 kv, contracting d=128
      float p[4][4];
#pragma unroll
      for (int ct = 0; ct < 4; ++ct) {
        f32x4 sc;
        sc[0] = 0.f; sc[1] = 0.f; sc[2] = 0.f; sc[3] = 0.f;
#pragma unroll
        for (int kd = 0; kd < 4; ++kd) {
          short8 bk = *(const short8*)&Kc[((ct << 4) + l15) * 128 +
                                          (((kd << 5) + (l4 << 3)) ^ xr)];
          sc = __builtin_amdgcn_mfma_f32_16x16x32_bf16(aq[kd], bk, sc, 0, 0, 0);
        }
#pragma unroll
        for (int r = 0; r < 4; ++r) p[ct][r] = sc[r] * scale2;
      }

      if ((t0 + 63) > (qw + CACHE_LEN)) {
#pragma unroll
        for (int ct = 0; ct < 4; ++ct)
#pragma unroll
          for (int r = 0; r < 4; ++r) {
            int qq = qw + (l4 << 2) + r + CACHE_LEN;
            if (t0 + (ct << 4) + l15 > qq) p[ct][r] = -1e30f;
          }
      }

      // per-row tile max (replicated across the 16-lane group)
      float mx[4];
#pragma unroll
      for (int r = 0; r < 4; ++r) {
        float m = fmaxf(fmaxf(p[0][r], p[1][r]), fmaxf(p[2][r], p[3][r]));
        m = fmaxf(m, __shfl_xor(m, 1));
        m = fmaxf(m, __shfl_xor(m, 2));
        m = fmaxf(m, __shfl_xor(m, 4));
        m = fmaxf(m, __shfl_xor(m, 8));
        mx[r] = m;
      }
      // defer-max (log2 units): rescale only when some row grew past 11
      bool grow = false;
#pragma unroll
      for (int r = 0; r < 4; ++r) grow = grow || (mx[r] > mrow[r] + 11.0f);
      if (__any(grow)) {
#pragma unroll
        for (int r = 0; r < 4; ++r) {
          float mn = fmaxf(mrow[r], mx[r]);
          float corr = exp2f(mrow[r] - mn);
          mrow[r] = mn;
          lrow[r] *= corr;
#pragma unroll
          for (int nd = 0; nd < 8; ++nd) accO[nd][r] *= corr;
        }
      }
#pragma unroll
      for (int r = 0; r < 4; ++r) {
        float rs = 0.f;
#pragma unroll
        for (int ct = 0; ct < 4; ++ct) {
          p[ct][r] = exp2f(p[ct][r] - mrow[r]);
          rs += p[ct][r];
        }
        rs += __shfl_xor(rs, 1);
        rs += __shfl_xor(rs, 2);
        rs += __shfl_xor(rs, 4);
        rs += __shfl_xor(rs, 8);
        lrow[r] += rs;
      }

      // P (D-layout) -> wave-private LDS -> A-fragment layout
#pragma unroll
      for (int ct = 0; ct < 4; ++ct)
#pragma unroll
        for (int r = 0; r < 4; ++r)
          Pls[wave][(l4 << 2) + r][(ct << 4) + l15] = f2bf(p[ct][r]);
      short8 pa0 = *(const short8*)&Pls[wave][l15][l4 << 3];
      short8 pa1 = *(const short8*)&Pls[wave][l15][32 + (l4 << 3)];

      // PV: O[q][d] += P[q][t] * V[t][d]; B-fragments from V^T rows
#pragma unroll
      for (int nd = 0; nd < 8; ++nd) {
        short8 bv0 = *(const short8*)&Vc[((nd << 4) + l15) * 64 + ((l4 << 3) ^ xr)];
        accO[nd] = __builtin_amdgcn_mfma_f32_16x16x32_bf16(pa0, bv0, accO[nd], 0, 0, 0);
        short8 bv1 = *(const short8*)&Vc[((nd << 4) + l15) * 64 + ((32 + (l4 << 3)) ^ xr)];
        accO[nd] = __builtin_amdgcn_mfma_f32_16x16x32_bf16(pa1, bv1, accO[nd], 0, 0, 0);
      }
      __syncthreads();   // drains prefetch (vmcnt) + LDS reads before overwrite
    }

    // phase epilogue
    float inv[4];
#pragma unroll
    for (int r = 0; r < 4; ++r) inv[r] = 1.0f / lrow[r];
#pragma unroll
    for (int nd = 0; nd < 8; ++nd) {
#pragma unroll
      for (int r = 0; r < 4; ++r) {
        float v = accO[nd][r] * inv[r];
        int q = qw + (l4 << 2) + r;
        int d = (nd << 4) + l15;
        resB[(size_t)q * E_DIM + hq * HD + d] = f2bf(v);
      }
    }
  }
#undef STAGE
}

// ---------------------------------------------------------------------------
extern "C" void kernel_launch(void* const* d_in, const int* in_sizes, int n_in,
                              void* d_out, int out_size, void* d_ws, size_t ws_size,
                              hipStream_t stream) {
  const float* x = (const float*)d_in[0];
  const float* w_q = (const float*)d_in[1];
  const float* w_k = (const float*)d_in[2];
  const float* w_v = (const float*)d_in[3];
  const float* w_o = (const float*)d_in[4];
  const float* k_cache = (const float*)d_in[5];
  const float* v_cache = (const float*)d_in[6];
  // d_in[7] = attention_mask: causal-with-offset; applied analytically.

  float* out = (float*)d_out;                          // [2048][4096]
  float* Kout = out + (size_t)S_LEN * E_DIM;           // [8][3072][128]

  // workspace layout (96 MiB):
  //   [ 0,16)  xb (x bf16) -> reused as resB   [16,32) Qb
  //   [32,38)  Kb  [8][3072][128]              [38,44) VbT [8][128][3072]
  //   [48,64)  wkvt (w_k^T | w_v^T)            [64,96) wbig (w_q^T, then w_o^T)
  char* ws = (char*)d_ws;
  const size_t MB = 1024 * 1024;
  u16* xb   = (u16*)(ws);
  u16* resB = (u16*)(ws);
  u16* Qb   = (u16*)(ws + 16 * MB);
  u16* Kb   = (u16*)(ws + 32 * MB);
  u16* VbT  = (u16*)(ws + 38 * MB);
  u16* wkvt = (u16*)(ws + 48 * MB);
  u16* wbig = (u16*)(ws + 64 * MB);

  cvt_x<<<dim3(8192), dim3(256), 0, stream>>>(x, xb);
  copy_caches<<<dim3(1024), dim3(256), 0, stream>>>(
      (const float4*)k_cache, (const float4*)v_cache,
      (float4*)Kout, (float4*)(Kout + KV_ELEMS), (uint2*)Kb);
  cvt_vcT<<<dim3(16, 2, 8), dim3(256), 0, stream>>>(v_cache, VbT);
  cvt_wt<<<dim3(1024), dim3(256), 0, stream>>>(w_k, wkvt, E_DIM, NHKV * HD);
  cvt_wt<<<dim3(1024), dim3(256), 0, stream>>>(w_v, wkvt + (size_t)1024 * E_DIM, E_DIM, NHKV * HD);
  cvt_wt<<<dim3(4096), dim3(256), 0, stream>>>(w_q, wbig, E_DIM, E_DIM);
  gemm2<1><<<dim3(16 * 16), dim3(256), 0, stream>>>(xb, wkvt, S_LEN, 2048, E_DIM, Kout, Kb, VbT);
  gemm2<0><<<dim3(16 * 32), dim3(256), 0, stream>>>(xb, wbig, S_LEN, E_DIM, E_DIM, nullptr, Qb, nullptr);
  cvt_wt<<<dim3(4096), dim3(256), 0, stream>>>(w_o, wbig, E_DIM, E_DIM);
  attn_fwd<<<dim3(256), dim3(512), 0, stream>>>(Qb, Kb, VbT, resB);
  gemm2<2><<<dim3(16 * 32), dim3(256), 0, stream>>>(resB, wbig, S_LEN, E_DIM, E_DIM, out, nullptr, nullptr);
}